// Round 7
// baseline (458.811 us; speedup 1.0000x reference)
//
#include <hip/hip_runtime.h>

// ---------------------------------------------------------------------------
// StandardMultiHeadAttention: B=2, S=2048, D=1024, H=16, Dh=64, causal.
// fp32->f16 convert -> QKV GEMM (epilogue scatters into MFMA-FRAGMENT-MAJOR
// layouts) -> flash attention (coalesced frag loads, S^T tiles, static-base
// softmax) -> bias-prefill + split-K output GEMM (fp32 atomics).
//
// Workspace (48 MB):
//   [0,8M)    xb : x f16 [4096,1024]
//   [8M,16M)  wb : Wq,Wk,Wv,Wo f16 (row=out, K-major)
//   [16M,24M) QF : Q frag-major (pre-scaled by 0.125*log2e)
//   [24M,32M) KF : K frag-major
//   [32M,40M) VF : V^T frag-major
//   [40M,48M) ob : attention output [B,S,1024] f16
//
// R6 post-mortem: attn ~40us at 2 waves/SIMD (serial exp->LDS->MFMA chain
// under-hidden); gemm_out at 1 block/CU (256 blocks).
// R7: attn kv-split 4 ways (4 waves/block, 16 waves/CU, KV traffic
// unchanged), l-shuffle deferred out of tile loop, 3-way LDS merge;
// gemm_out split-K=2 with fp32 atomicAdd onto bias-prefilled d_out.
// ---------------------------------------------------------------------------

typedef _Float16 f16x8 __attribute__((ext_vector_type(8)));
typedef _Float16 f16x4 __attribute__((ext_vector_type(4)));
typedef _Float16 f16x2 __attribute__((ext_vector_type(2)));
typedef float f32x4 __attribute__((ext_vector_type(4)));

#define S_  2048
#define DM  1024
#define NH  16
#define DH  64

__device__ __forceinline__ void gload_lds16(const void* g, void* s) {
  __builtin_amdgcn_global_load_lds(
      (const __attribute__((address_space(1))) void*)g,
      (__attribute__((address_space(3))) void*)s, 16, 0, 0);
}

__device__ __forceinline__ f16x2 pkrtz(float a, float b) {
  return __builtin_bit_cast(f16x2, __builtin_amdgcn_cvt_pkrtz(a, b));
}

// ----------------------------- convert kernels -----------------------------

__global__ void cvt_x_kernel(const float* __restrict__ src,
                             _Float16* __restrict__ dst) {
  const int i = blockIdx.x * 256 + threadIdx.x;
  const float4 v = ((const float4*)src)[i];
  f16x4 h;
  h[0] = (_Float16)v.x; h[1] = (_Float16)v.y;
  h[2] = (_Float16)v.z; h[3] = (_Float16)v.w;
  ((f16x4*)dst)[i] = h;
}

__global__ void cvt_w_kernel(const float* __restrict__ w0,
                             const float* __restrict__ w1,
                             const float* __restrict__ w2,
                             const float* __restrict__ w3,
                             _Float16* __restrict__ dst) {
  const int y = blockIdx.y;
  const float* src = (y == 0) ? w0 : (y == 1) ? w1 : (y == 2) ? w2 : w3;
  const int i = blockIdx.x * 256 + threadIdx.x;
  const float4 v = ((const float4*)src)[i];
  f16x4 h;
  h[0] = (_Float16)v.x; h[1] = (_Float16)v.y;
  h[2] = (_Float16)v.z; h[3] = (_Float16)v.w;
  ((f16x4*)(dst + (size_t)y * (DM * DM)))[i] = h;
}

// d_out <- bias broadcast (split-K gemm_out atomically accumulates onto it)
__global__ void bias_fill_kernel(const float* __restrict__ bo,
                                 float* __restrict__ out) {
  const int i = blockIdx.x * 256 + threadIdx.x;   // float4 idx, 4096*256 total
  ((float4*)out)[i] = ((const float4*)bo)[i & 255];
}

// ------------------------------- GEMM core ---------------------------------

__device__ __forceinline__ void gemm_core(
    const _Float16* __restrict__ A, const _Float16* __restrict__ W,
    _Float16* As, _Float16* Ws, f32x4 acc[4][4], int m0, int n0,
    int kbeg, int kend)
{
  const int t = threadIdx.x;
  const int w = t >> 6, l = t & 63;
  const int quad = l >> 4, ln = l & 15;
  const int wm = (w >> 1) << 6, wn = (w & 1) << 6;
  const int srow = l >> 2, scol = (l & 3) << 3;

  for (int k0 = kbeg; k0 < kend; k0 += 32) {
#pragma unroll
    for (int i = 0; i < 2; ++i) {
      const int ra = w * 32 + i * 16;
      gload_lds16(&A[(size_t)(m0 + ra + srow) * DM + k0 + scol], &As[ra * 32]);
      gload_lds16(&W[(size_t)(n0 + ra + srow) * DM + k0 + scol], &Ws[ra * 32]);
    }
    __syncthreads();

    f16x8 af[4], bf[4];
#pragma unroll
    for (int mi = 0; mi < 4; ++mi)
      af[mi] = *(const f16x8*)&As[(wm + mi * 16 + ln) * 32 + quad * 8];
#pragma unroll
    for (int ni = 0; ni < 4; ++ni)
      bf[ni] = *(const f16x8*)&Ws[(wn + ni * 16 + ln) * 32 + quad * 8];
#pragma unroll
    for (int mi = 0; mi < 4; ++mi)
#pragma unroll
      for (int ni = 0; ni < 4; ++ni)
        acc[mi][ni] = __builtin_amdgcn_mfma_f32_16x16x32_f16(
            af[mi], bf[ni], acc[mi][ni], 0, 0, 0);
    __syncthreads();
  }
}

// z=0: Q (bias, *0.125*log2e, QF layout); z=1: K (bias, KF layout);
// z=2: V (bias, VF layout)
__global__ __launch_bounds__(256, 2) void gemm_qkv_kernel(
    const _Float16* __restrict__ xb, const _Float16* __restrict__ wb,
    const float* __restrict__ bq, const float* __restrict__ bk,
    const float* __restrict__ bv, _Float16* __restrict__ qkv)
{
  __shared__ _Float16 As[128 * 32];
  __shared__ _Float16 Ws[128 * 32];
  const int z = blockIdx.z;
  const _Float16* W = wb + (size_t)z * (DM * DM);
  const float* bias = (z == 0) ? bq : ((z == 1) ? bk : bv);
  _Float16* out = qkv + (size_t)z * 4194304;

  const f32x4 z4 = {0.f, 0.f, 0.f, 0.f};
  f32x4 acc[4][4];
#pragma unroll
  for (int mi = 0; mi < 4; ++mi)
#pragma unroll
    for (int ni = 0; ni < 4; ++ni) acc[mi][ni] = z4;

  const int m0 = blockIdx.y * 128, n0 = blockIdx.x * 128;
  gemm_core(xb, W, As, Ws, acc, m0, n0, 0, DM);

  const int t = threadIdx.x, w = t >> 6, l = t & 63;
  const int quad = l >> 4, ln = l & 15;
  const int wm = (w >> 1) << 6, wn = (w & 1) << 6;
  // fold 1/sqrt(Dh) * log2(e) into Q so attention uses exp2
  const float scale = (z == 0) ? 0.18033688f : 1.0f;

#pragma unroll
  for (int ni = 0; ni < 4; ++ni) {
    const int c = n0 + wn + ni * 16 + ln;
    const float bias_c = bias[c];
    const int h = c >> 6, d = c & 63;
#pragma unroll
    for (int mi = 0; mi < 4; ++mi) {
      const int mb = m0 + wm + mi * 16 + quad * 4;
#pragma unroll
      for (int r = 0; r < 4; ++r) {
        const int mg = mb + r;
        const int b = mg >> 11, s = mg & 2047;
        const int bh = b * NH + h;
        const float v = (acc[mi][ni][r] + bias_c) * scale;
        size_t idx;
        if (z == 2)
          idx = (size_t)bh * 131072 + (s >> 5) * 2048 + (d >> 4) * 512 +
                ((s >> 3) & 3) * 128 + (d & 15) * 8 + (s & 7);
        else
          idx = (size_t)bh * 131072 + (s >> 4) * 1024 + (d >> 5) * 512 +
                ((d >> 3) & 3) * 128 + (s & 15) * 8 + (d & 7);
        out[idx] = (_Float16)v;
      }
    }
  }
}

// split-K=2: z = K-half; atomically accumulates onto bias-prefilled out.
__global__ __launch_bounds__(256, 2) void gemm_out_kernel(
    const _Float16* __restrict__ ob, const _Float16* __restrict__ wo,
    float* __restrict__ out)
{
  __shared__ _Float16 As[128 * 32];
  __shared__ _Float16 Ws[128 * 32];
  const f32x4 z4 = {0.f, 0.f, 0.f, 0.f};
  f32x4 acc[4][4];
#pragma unroll
  for (int mi = 0; mi < 4; ++mi)
#pragma unroll
    for (int ni = 0; ni < 4; ++ni) acc[mi][ni] = z4;

  const int m0 = blockIdx.y * 128, n0 = blockIdx.x * 128;
  const int kbeg = blockIdx.z * 512;
  gemm_core(ob, wo, As, Ws, acc, m0, n0, kbeg, kbeg + 512);

  const int t = threadIdx.x, w = t >> 6, l = t & 63;
  const int quad = l >> 4, ln = l & 15;
  const int wm = (w >> 1) << 6, wn = (w & 1) << 6;

#pragma unroll
  for (int ni = 0; ni < 4; ++ni) {
    const int c = n0 + wn + ni * 16 + ln;
#pragma unroll
    for (int mi = 0; mi < 4; ++mi) {
      const int mb = m0 + wm + mi * 16 + quad * 4;
#pragma unroll
      for (int r = 0; r < 4; ++r)
        atomicAdd(&out[(size_t)(mb + r) * DM + c], acc[mi][ni][r]);
    }
  }
}

// ---------------------------- flash attention ------------------------------
// 1024 blocks x 4 waves (16 waves/CU). Block = (head bh, pair p): wave w
// takes kv tiles t == w (mod 4) for q-tiles {63-p, p} (65 tiles/pair,
// ~16/wave, all waves equal; disjoint tiles -> KV traffic unchanged).
// Partial (O,l) merged via LDS (static-base softmax => plain sum).
// l quad-reduction deferred out of the tile loop (per-lane partials).

struct KVfrag { f16x8 k[4]; f16x8 v[4]; };

__device__ __forceinline__ KVfrag load_tile(const _Float16* __restrict__ kb_,
                                            const _Float16* __restrict__ vb_,
                                            int t, int l) {
  KVfrag f;
#pragma unroll
  for (int i = 0; i < 4; ++i)
    f.k[i] = *(const f16x8*)(kb_ + (size_t)(t * 4 + i) * 512 + l * 8);
#pragma unroll
  for (int i = 0; i < 4; ++i)
    f.v[i] = *(const f16x8*)(vb_ + (size_t)(t * 4 + i) * 512 + l * 8);
  return f;
}

template <bool DIAG>
__device__ __forceinline__ void compute_tile(
    const KVfrag& kv, const f16x8 (&qf)[2][2], f32x4 (&oacc)[4][2],
    float (&l_i)[2], _Float16* Ps, int quad, int ln)
{
  const f32x4 z4 = {0.f, 0.f, 0.f, 0.f};
  f32x4 sacc[2][2];
#pragma unroll
  for (int mi = 0; mi < 2; ++mi)
#pragma unroll
    for (int qc = 0; qc < 2; ++qc) sacc[mi][qc] = z4;

  // S^T tile: A = K frag (m=kv), B = Q frag (n=q)
#pragma unroll
  for (int ks = 0; ks < 2; ++ks)
#pragma unroll
    for (int mi = 0; mi < 2; ++mi)
#pragma unroll
      for (int qc = 0; qc < 2; ++qc)
        sacc[mi][qc] = __builtin_amdgcn_mfma_f32_16x16x32_f16(
            kv.k[mi * 2 + ks], qf[qc][ks], sacc[mi][qc], 0, 0, 0);

  // static-base softmax: p = 2^s (Q pre-scaled by 0.125*log2e);
  // l_i accumulates per-lane (own-quad rows); quad reduction deferred.
  const int sw = (ln & 3) << 1;   // even XOR key: keeps 16B read alignment
#pragma unroll
  for (int qc = 0; qc < 2; ++qc) {
    float rs = 0.f;
#pragma unroll
    for (int mi = 0; mi < 2; ++mi) {
      float p[4];
#pragma unroll
      for (int r = 0; r < 4; ++r) {
        p[r] = __builtin_amdgcn_exp2f(sacc[mi][qc][r]);
        if (DIAG && (mi * 16 + quad * 4 + r > qc * 16 + ln)) p[r] = 0.f;
        rs += p[r];
      }
      const f16x2 lo = pkrtz(p[0], p[1]);
      const f16x2 hi = pkrtz(p[2], p[3]);
      const f16x4 pk = __builtin_shufflevector(lo, hi, 0, 1, 2, 3);
      const int g = (mi * 4 + quad) ^ sw;          // 8B granule, swizzled
      *(f16x4*)&Ps[(qc * 16 + ln) * 40 + g * 4] = pk;
    }
    l_i[qc] += rs;
  }

  // P^T B-frags (row q=ln, kv contiguous) — wave-private, no barrier
  f16x8 pb[2];
#pragma unroll
  for (int qc = 0; qc < 2; ++qc) {
    const int g2 = (quad * 2) ^ sw;                // even -> pair contiguous
    pb[qc] = *(const f16x8*)&Ps[(qc * 16 + ln) * 40 + g2 * 4];
  }

  // O^T += V^T * P^T
#pragma unroll
  for (int di = 0; di < 4; ++di)
#pragma unroll
    for (int qc = 0; qc < 2; ++qc)
      oacc[di][qc] = __builtin_amdgcn_mfma_f32_16x16x32_f16(
          kv.v[di], pb[qc], oacc[di][qc], 0, 0, 0);
}

__global__ __launch_bounds__(256, 4) void attn_kernel(
    const _Float16* __restrict__ QF, const _Float16* __restrict__ KF,
    const _Float16* __restrict__ VF, _Float16* __restrict__ Ob)
{
  __shared__ _Float16 Ps[4 * 32 * 40];   // per-wave P transpose buffers
  __shared__ float mrg[3 * 64 * 36];     // cross-wave (O,l) merge, 16B-aligned

  // block -> (bh, pair): XCD x = i&7 sees 4 heads (2MB KV <= 4MB L2/XCD)
  const int i = blockIdx.x;
  const int bh = ((i & 7) << 2) | ((i >> 3) & 3);
  const int p = i >> 5;                  // pair index 0..31

  const int tid = threadIdx.x;
  const int w = tid >> 6, l = tid & 63;  // w = kv residue mod 4
  const int quad = l >> 4, ln = l & 15;

  const _Float16* qb_ = QF + (size_t)bh * 131072;
  const _Float16* kb_ = KF + (size_t)bh * 131072;
  const _Float16* vb_ = VF + (size_t)bh * 131072;
  _Float16* psw = Ps + w * (32 * 40);
  const int bidx = bh >> 4, h = bh & 15;

  const f32x4 z4 = {0.f, 0.f, 0.f, 0.f};

#pragma unroll
  for (int mem = 0; mem < 2; ++mem) {
    const int qw = (mem == 0) ? (63 - p) : p;
    const int q0 = qw << 5;

    f16x8 qf[2][2];
#pragma unroll
    for (int qc = 0; qc < 2; ++qc)
#pragma unroll
      for (int ks = 0; ks < 2; ++ks)
        qf[qc][ks] = *(const f16x8*)
            (qb_ + (size_t)((2 * qw + qc) * 2 + ks) * 512 + l * 8);

    f32x4 oacc[4][2];
#pragma unroll
    for (int di = 0; di < 4; ++di)
#pragma unroll
      for (int qc = 0; qc < 2; ++qc) oacc[di][qc] = z4;
    float l_i[2] = {0.f, 0.f};

    // kv tiles t = w, w+4, ..., <= qw ; diag (t==qw) iff (qw-w)%4==0
    const int n = (qw >= w) ? (((qw - w) >> 2) + 1) : 0;
    if (n > 0) {
      KVfrag b0 = load_tile(kb_, vb_, w, l);
      KVfrag b1;
      for (int k = 0; k + 1 < n; ++k) {
        const int tnext = w + 4 * (k + 1);
        if ((k & 1) == 0) {
          b1 = load_tile(kb_, vb_, tnext, l);
          compute_tile<false>(b0, qf, oacc, l_i, psw, quad, ln);
        } else {
          b0 = load_tile(kb_, vb_, tnext, l);
          compute_tile<false>(b1, qf, oacc, l_i, psw, quad, ln);
        }
      }
      const KVfrag& last = ((n - 1) & 1) ? b1 : b0;
      if (((qw - w) & 3) == 0)
        compute_tile<true>(last, qf, oacc, l_i, psw, quad, ln);
      else
        compute_tile<false>(last, qf, oacc, l_i, psw, quad, ln);
    }

    // deferred quad-reduction of l partials (2 shuffles per qc, once)
#pragma unroll
    for (int qc = 0; qc < 2; ++qc) {
      float s = l_i[qc];
      s += __shfl_xor(s, 16);
      s += __shfl_xor(s, 32);
      l_i[qc] = s;
    }

    // merge partials: waves 1..3 -> LDS, barrier, wave0 adds + writes O
    if (w != 0) {
      float* m_ = &mrg[((w - 1) * 64 + l) * 36];
#pragma unroll
      for (int di = 0; di < 4; ++di)
#pragma unroll
        for (int qc = 0; qc < 2; ++qc)
          *(f32x4*)(m_ + di * 8 + qc * 4) = oacc[di][qc];
      m_[32] = l_i[0];
      m_[33] = l_i[1];
    }
    __syncthreads();
    if (w == 0) {
#pragma unroll
      for (int ww = 0; ww < 3; ++ww) {
        const float* m_ = &mrg[(ww * 64 + l) * 36];
#pragma unroll
        for (int di = 0; di < 4; ++di)
#pragma unroll
          for (int qc = 0; qc < 2; ++qc)
            oacc[di][qc] += *(const f32x4*)(m_ + di * 8 + qc * 4);
        l_i[0] += m_[32];
        l_i[1] += m_[33];
      }
#pragma unroll
      for (int qc = 0; qc < 2; ++qc) {
        const float inv = 1.0f / l_i[qc];
        const int q = q0 + qc * 16 + ln;
        _Float16* orow = Ob + (size_t)(bidx * S_ + q) * DM + h * DH + quad * 4;
#pragma unroll
        for (int di = 0; di < 4; ++di) {
          f16x4 o4;
#pragma unroll
          for (int r = 0; r < 4; ++r)
            o4[r] = (_Float16)(oacc[di][qc][r] * inv);
          *(f16x4*)(orow + di * 16) = o4;
        }
      }
    }
    __syncthreads();   // mrg reused by member 2
  }
}

// ------------------------------- launcher ----------------------------------

extern "C" void kernel_launch(void* const* d_in, const int* in_sizes, int n_in,
                              void* d_out, int out_size, void* d_ws, size_t ws_size,
                              hipStream_t stream) {
  (void)in_sizes; (void)n_in; (void)out_size; (void)ws_size;
  const float* x  = (const float*)d_in[0];
  const float* Wq = (const float*)d_in[1];
  const float* bq = (const float*)d_in[2];
  const float* Wk = (const float*)d_in[3];
  const float* bk = (const float*)d_in[4];
  const float* Wv = (const float*)d_in[5];
  const float* bv = (const float*)d_in[6];
  const float* Wo = (const float*)d_in[7];
  const float* bo = (const float*)d_in[8];

  char* ws = (char*)d_ws;
  _Float16* xb  = (_Float16*)(ws);                      // 8 MB
  _Float16* wb  = (_Float16*)(ws + (8u << 20));         // 4 x 2 MB
  _Float16* qkv = (_Float16*)(ws + (16u << 20));        // QF,KF,VF 8 MB each
  _Float16* ob  = (_Float16*)(ws + (40u << 20));        // 8 MB

  cvt_x_kernel<<<dim3(4096), dim3(256), 0, stream>>>(x, xb);
  cvt_w_kernel<<<dim3(1024, 4), dim3(256), 0, stream>>>(Wq, Wk, Wv, Wo, wb);
  bias_fill_kernel<<<dim3(4096), dim3(256), 0, stream>>>(bo, (float*)d_out);
  gemm_qkv_kernel<<<dim3(8, 32, 3), dim3(256), 0, stream>>>(xb, wb, bq, bk, bv, qkv);
  attn_kernel<<<dim3(1024), dim3(256), 0, stream>>>(
      qkv, qkv + 4194304, qkv + 2 * 4194304, ob);
  gemm_out_kernel<<<dim3(8, 32, 2), dim3(256), 0, stream>>>(
      ob, wb + (size_t)3 * DM * DM, (float*)d_out);
}

// Round 8
// 318.273 us; speedup vs baseline: 1.4416x; 1.4416x over previous
//
#include <hip/hip_runtime.h>

// ---------------------------------------------------------------------------
// StandardMultiHeadAttention: B=2, S=2048, D=1024, H=16, Dh=64, causal.
// fp32->f16 convert -> QKV GEMM (epilogue scatters into MFMA-FRAGMENT-MAJOR
// layouts) -> flash attention (coalesced frag loads, S^T tiles, static-base
// softmax) -> bias-prefill + split-K output GEMM (fp32 atomics).
//
// Workspace (48 MB):
//   [0,8M)    xb : x f16 [4096,1024]
//   [8M,16M)  wb : Wq,Wk,Wv,Wo f16 (row=out, K-major)
//   [16M,24M) QF : Q frag-major (pre-scaled by 0.125*log2e)
//   [24M,32M) KF : K frag-major
//   [32M,40M) VF : V^T frag-major
//   [40M,48M) ob : attention output [B,S,1024] f16
//
// R7 post-mortem: __launch_bounds__(256,4) capped unified VGPR+AGPR at 128
// < ~150 live -> massive scratch spills (FETCH 538MB, WRITE 790MB, 290us).
// R8: identical structure, launch_bounds (256,3) -> cap ~170 regs, no
// spill, 12 waves/CU (vs R6's 8). Demand measured at 112 VGPR in R4.
// ---------------------------------------------------------------------------

typedef _Float16 f16x8 __attribute__((ext_vector_type(8)));
typedef _Float16 f16x4 __attribute__((ext_vector_type(4)));
typedef _Float16 f16x2 __attribute__((ext_vector_type(2)));
typedef float f32x4 __attribute__((ext_vector_type(4)));

#define S_  2048
#define DM  1024
#define NH  16
#define DH  64

__device__ __forceinline__ void gload_lds16(const void* g, void* s) {
  __builtin_amdgcn_global_load_lds(
      (const __attribute__((address_space(1))) void*)g,
      (__attribute__((address_space(3))) void*)s, 16, 0, 0);
}

__device__ __forceinline__ f16x2 pkrtz(float a, float b) {
  return __builtin_bit_cast(f16x2, __builtin_amdgcn_cvt_pkrtz(a, b));
}

// ----------------------------- convert kernels -----------------------------

__global__ void cvt_x_kernel(const float* __restrict__ src,
                             _Float16* __restrict__ dst) {
  const int i = blockIdx.x * 256 + threadIdx.x;
  const float4 v = ((const float4*)src)[i];
  f16x4 h;
  h[0] = (_Float16)v.x; h[1] = (_Float16)v.y;
  h[2] = (_Float16)v.z; h[3] = (_Float16)v.w;
  ((f16x4*)dst)[i] = h;
}

__global__ void cvt_w_kernel(const float* __restrict__ w0,
                             const float* __restrict__ w1,
                             const float* __restrict__ w2,
                             const float* __restrict__ w3,
                             _Float16* __restrict__ dst) {
  const int y = blockIdx.y;
  const float* src = (y == 0) ? w0 : (y == 1) ? w1 : (y == 2) ? w2 : w3;
  const int i = blockIdx.x * 256 + threadIdx.x;
  const float4 v = ((const float4*)src)[i];
  f16x4 h;
  h[0] = (_Float16)v.x; h[1] = (_Float16)v.y;
  h[2] = (_Float16)v.z; h[3] = (_Float16)v.w;
  ((f16x4*)(dst + (size_t)y * (DM * DM)))[i] = h;
}

// d_out <- bias broadcast (split-K gemm_out atomically accumulates onto it)
__global__ void bias_fill_kernel(const float* __restrict__ bo,
                                 float* __restrict__ out) {
  const int i = blockIdx.x * 256 + threadIdx.x;   // float4 idx, 4096*256 total
  ((float4*)out)[i] = ((const float4*)bo)[i & 255];
}

// ------------------------------- GEMM core ---------------------------------

__device__ __forceinline__ void gemm_core(
    const _Float16* __restrict__ A, const _Float16* __restrict__ W,
    _Float16* As, _Float16* Ws, f32x4 acc[4][4], int m0, int n0,
    int kbeg, int kend)
{
  const int t = threadIdx.x;
  const int w = t >> 6, l = t & 63;
  const int quad = l >> 4, ln = l & 15;
  const int wm = (w >> 1) << 6, wn = (w & 1) << 6;
  const int srow = l >> 2, scol = (l & 3) << 3;

  for (int k0 = kbeg; k0 < kend; k0 += 32) {
#pragma unroll
    for (int i = 0; i < 2; ++i) {
      const int ra = w * 32 + i * 16;
      gload_lds16(&A[(size_t)(m0 + ra + srow) * DM + k0 + scol], &As[ra * 32]);
      gload_lds16(&W[(size_t)(n0 + ra + srow) * DM + k0 + scol], &Ws[ra * 32]);
    }
    __syncthreads();

    f16x8 af[4], bf[4];
#pragma unroll
    for (int mi = 0; mi < 4; ++mi)
      af[mi] = *(const f16x8*)&As[(wm + mi * 16 + ln) * 32 + quad * 8];
#pragma unroll
    for (int ni = 0; ni < 4; ++ni)
      bf[ni] = *(const f16x8*)&Ws[(wn + ni * 16 + ln) * 32 + quad * 8];
#pragma unroll
    for (int mi = 0; mi < 4; ++mi)
#pragma unroll
      for (int ni = 0; ni < 4; ++ni)
        acc[mi][ni] = __builtin_amdgcn_mfma_f32_16x16x32_f16(
            af[mi], bf[ni], acc[mi][ni], 0, 0, 0);
    __syncthreads();
  }
}

// z=0: Q (bias, *0.125*log2e, QF layout); z=1: K (bias, KF layout);
// z=2: V (bias, VF layout)
__global__ __launch_bounds__(256, 2) void gemm_qkv_kernel(
    const _Float16* __restrict__ xb, const _Float16* __restrict__ wb,
    const float* __restrict__ bq, const float* __restrict__ bk,
    const float* __restrict__ bv, _Float16* __restrict__ qkv)
{
  __shared__ _Float16 As[128 * 32];
  __shared__ _Float16 Ws[128 * 32];
  const int z = blockIdx.z;
  const _Float16* W = wb + (size_t)z * (DM * DM);
  const float* bias = (z == 0) ? bq : ((z == 1) ? bk : bv);
  _Float16* out = qkv + (size_t)z * 4194304;

  const f32x4 z4 = {0.f, 0.f, 0.f, 0.f};
  f32x4 acc[4][4];
#pragma unroll
  for (int mi = 0; mi < 4; ++mi)
#pragma unroll
    for (int ni = 0; ni < 4; ++ni) acc[mi][ni] = z4;

  const int m0 = blockIdx.y * 128, n0 = blockIdx.x * 128;
  gemm_core(xb, W, As, Ws, acc, m0, n0, 0, DM);

  const int t = threadIdx.x, w = t >> 6, l = t & 63;
  const int quad = l >> 4, ln = l & 15;
  const int wm = (w >> 1) << 6, wn = (w & 1) << 6;
  // fold 1/sqrt(Dh) * log2(e) into Q so attention uses exp2
  const float scale = (z == 0) ? 0.18033688f : 1.0f;

#pragma unroll
  for (int ni = 0; ni < 4; ++ni) {
    const int c = n0 + wn + ni * 16 + ln;
    const float bias_c = bias[c];
    const int h = c >> 6, d = c & 63;
#pragma unroll
    for (int mi = 0; mi < 4; ++mi) {
      const int mb = m0 + wm + mi * 16 + quad * 4;
#pragma unroll
      for (int r = 0; r < 4; ++r) {
        const int mg = mb + r;
        const int b = mg >> 11, s = mg & 2047;
        const int bh = b * NH + h;
        const float v = (acc[mi][ni][r] + bias_c) * scale;
        size_t idx;
        if (z == 2)
          idx = (size_t)bh * 131072 + (s >> 5) * 2048 + (d >> 4) * 512 +
                ((s >> 3) & 3) * 128 + (d & 15) * 8 + (s & 7);
        else
          idx = (size_t)bh * 131072 + (s >> 4) * 1024 + (d >> 5) * 512 +
                ((d >> 3) & 3) * 128 + (s & 15) * 8 + (d & 7);
        out[idx] = (_Float16)v;
      }
    }
  }
}

// split-K=2: z = K-half; atomically accumulates onto bias-prefilled out.
__global__ __launch_bounds__(256, 2) void gemm_out_kernel(
    const _Float16* __restrict__ ob, const _Float16* __restrict__ wo,
    float* __restrict__ out)
{
  __shared__ _Float16 As[128 * 32];
  __shared__ _Float16 Ws[128 * 32];
  const f32x4 z4 = {0.f, 0.f, 0.f, 0.f};
  f32x4 acc[4][4];
#pragma unroll
  for (int mi = 0; mi < 4; ++mi)
#pragma unroll
    for (int ni = 0; ni < 4; ++ni) acc[mi][ni] = z4;

  const int m0 = blockIdx.y * 128, n0 = blockIdx.x * 128;
  const int kbeg = blockIdx.z * 512;
  gemm_core(ob, wo, As, Ws, acc, m0, n0, kbeg, kbeg + 512);

  const int t = threadIdx.x, w = t >> 6, l = t & 63;
  const int quad = l >> 4, ln = l & 15;
  const int wm = (w >> 1) << 6, wn = (w & 1) << 6;

#pragma unroll
  for (int ni = 0; ni < 4; ++ni) {
    const int c = n0 + wn + ni * 16 + ln;
#pragma unroll
    for (int mi = 0; mi < 4; ++mi) {
      const int mb = m0 + wm + mi * 16 + quad * 4;
#pragma unroll
      for (int r = 0; r < 4; ++r)
        atomicAdd(&out[(size_t)(mb + r) * DM + c], acc[mi][ni][r]);
    }
  }
}

// ---------------------------- flash attention ------------------------------
// 1024 blocks x 4 waves (12 waves/CU at 3 blocks/CU). Block = (head bh,
// pair p): wave w takes kv tiles t == w (mod 4) for q-tiles {63-p, p}
// (65 tiles/pair, ~16/wave, all waves equal; disjoint tiles -> KV traffic
// unchanged). Partial (O,l) merged via LDS. l quad-reduction deferred.

struct KVfrag { f16x8 k[4]; f16x8 v[4]; };

__device__ __forceinline__ KVfrag load_tile(const _Float16* __restrict__ kb_,
                                            const _Float16* __restrict__ vb_,
                                            int t, int l) {
  KVfrag f;
#pragma unroll
  for (int i = 0; i < 4; ++i)
    f.k[i] = *(const f16x8*)(kb_ + (size_t)(t * 4 + i) * 512 + l * 8);
#pragma unroll
  for (int i = 0; i < 4; ++i)
    f.v[i] = *(const f16x8*)(vb_ + (size_t)(t * 4 + i) * 512 + l * 8);
  return f;
}

template <bool DIAG>
__device__ __forceinline__ void compute_tile(
    const KVfrag& kv, const f16x8 (&qf)[2][2], f32x4 (&oacc)[4][2],
    float (&l_i)[2], _Float16* Ps, int quad, int ln)
{
  const f32x4 z4 = {0.f, 0.f, 0.f, 0.f};
  f32x4 sacc[2][2];
#pragma unroll
  for (int mi = 0; mi < 2; ++mi)
#pragma unroll
    for (int qc = 0; qc < 2; ++qc) sacc[mi][qc] = z4;

  // S^T tile: A = K frag (m=kv), B = Q frag (n=q)
#pragma unroll
  for (int ks = 0; ks < 2; ++ks)
#pragma unroll
    for (int mi = 0; mi < 2; ++mi)
#pragma unroll
      for (int qc = 0; qc < 2; ++qc)
        sacc[mi][qc] = __builtin_amdgcn_mfma_f32_16x16x32_f16(
            kv.k[mi * 2 + ks], qf[qc][ks], sacc[mi][qc], 0, 0, 0);

  // static-base softmax: p = 2^s (Q pre-scaled by 0.125*log2e);
  // l_i accumulates per-lane (own-quad rows); quad reduction deferred.
  const int sw = (ln & 3) << 1;   // even XOR key: keeps 16B read alignment
#pragma unroll
  for (int qc = 0; qc < 2; ++qc) {
    float rs = 0.f;
#pragma unroll
    for (int mi = 0; mi < 2; ++mi) {
      float p[4];
#pragma unroll
      for (int r = 0; r < 4; ++r) {
        p[r] = __builtin_amdgcn_exp2f(sacc[mi][qc][r]);
        if (DIAG && (mi * 16 + quad * 4 + r > qc * 16 + ln)) p[r] = 0.f;
        rs += p[r];
      }
      const f16x2 lo = pkrtz(p[0], p[1]);
      const f16x2 hi = pkrtz(p[2], p[3]);
      const f16x4 pk = __builtin_shufflevector(lo, hi, 0, 1, 2, 3);
      const int g = (mi * 4 + quad) ^ sw;          // 8B granule, swizzled
      *(f16x4*)&Ps[(qc * 16 + ln) * 40 + g * 4] = pk;
    }
    l_i[qc] += rs;
  }

  // P^T B-frags (row q=ln, kv contiguous) — wave-private, no barrier
  f16x8 pb[2];
#pragma unroll
  for (int qc = 0; qc < 2; ++qc) {
    const int g2 = (quad * 2) ^ sw;                // even -> pair contiguous
    pb[qc] = *(const f16x8*)&Ps[(qc * 16 + ln) * 40 + g2 * 4];
  }

  // O^T += V^T * P^T
#pragma unroll
  for (int di = 0; di < 4; ++di)
#pragma unroll
    for (int qc = 0; qc < 2; ++qc)
      oacc[di][qc] = __builtin_amdgcn_mfma_f32_16x16x32_f16(
          kv.v[di], pb[qc], oacc[di][qc], 0, 0, 0);
}

__global__ __launch_bounds__(256, 3) void attn_kernel(
    const _Float16* __restrict__ QF, const _Float16* __restrict__ KF,
    const _Float16* __restrict__ VF, _Float16* __restrict__ Ob)
{
  __shared__ _Float16 Ps[4 * 32 * 40];   // per-wave P transpose buffers
  __shared__ float mrg[3 * 64 * 36];     // cross-wave (O,l) merge, 16B-aligned

  // block -> (bh, pair): XCD x = i&7 sees 4 heads (2MB KV <= 4MB L2/XCD)
  const int i = blockIdx.x;
  const int bh = ((i & 7) << 2) | ((i >> 3) & 3);
  const int p = i >> 5;                  // pair index 0..31

  const int tid = threadIdx.x;
  const int w = tid >> 6, l = tid & 63;  // w = kv residue mod 4
  const int quad = l >> 4, ln = l & 15;

  const _Float16* qb_ = QF + (size_t)bh * 131072;
  const _Float16* kb_ = KF + (size_t)bh * 131072;
  const _Float16* vb_ = VF + (size_t)bh * 131072;
  _Float16* psw = Ps + w * (32 * 40);
  const int bidx = bh >> 4, h = bh & 15;

  const f32x4 z4 = {0.f, 0.f, 0.f, 0.f};

#pragma unroll
  for (int mem = 0; mem < 2; ++mem) {
    const int qw = (mem == 0) ? (63 - p) : p;
    const int q0 = qw << 5;

    f16x8 qf[2][2];
#pragma unroll
    for (int qc = 0; qc < 2; ++qc)
#pragma unroll
      for (int ks = 0; ks < 2; ++ks)
        qf[qc][ks] = *(const f16x8*)
            (qb_ + (size_t)((2 * qw + qc) * 2 + ks) * 512 + l * 8);

    f32x4 oacc[4][2];
#pragma unroll
    for (int di = 0; di < 4; ++di)
#pragma unroll
      for (int qc = 0; qc < 2; ++qc) oacc[di][qc] = z4;
    float l_i[2] = {0.f, 0.f};

    // kv tiles t = w, w+4, ..., <= qw ; diag (t==qw) iff (qw-w)%4==0
    const int n = (qw >= w) ? (((qw - w) >> 2) + 1) : 0;
    if (n > 0) {
      KVfrag b0 = load_tile(kb_, vb_, w, l);
      KVfrag b1;
      for (int k = 0; k + 1 < n; ++k) {
        const int tnext = w + 4 * (k + 1);
        if ((k & 1) == 0) {
          b1 = load_tile(kb_, vb_, tnext, l);
          compute_tile<false>(b0, qf, oacc, l_i, psw, quad, ln);
        } else {
          b0 = load_tile(kb_, vb_, tnext, l);
          compute_tile<false>(b1, qf, oacc, l_i, psw, quad, ln);
        }
      }
      const KVfrag& last = ((n - 1) & 1) ? b1 : b0;
      if (((qw - w) & 3) == 0)
        compute_tile<true>(last, qf, oacc, l_i, psw, quad, ln);
      else
        compute_tile<false>(last, qf, oacc, l_i, psw, quad, ln);
    }

    // deferred quad-reduction of l partials (2 shuffles per qc, once)
#pragma unroll
    for (int qc = 0; qc < 2; ++qc) {
      float s = l_i[qc];
      s += __shfl_xor(s, 16);
      s += __shfl_xor(s, 32);
      l_i[qc] = s;
    }

    // merge partials: waves 1..3 -> LDS, barrier, wave0 adds + writes O
    if (w != 0) {
      float* m_ = &mrg[((w - 1) * 64 + l) * 36];
#pragma unroll
      for (int di = 0; di < 4; ++di)
#pragma unroll
        for (int qc = 0; qc < 2; ++qc)
          *(f32x4*)(m_ + di * 8 + qc * 4) = oacc[di][qc];
      m_[32] = l_i[0];
      m_[33] = l_i[1];
    }
    __syncthreads();
    if (w == 0) {
#pragma unroll
      for (int ww = 0; ww < 3; ++ww) {
        const float* m_ = &mrg[(ww * 64 + l) * 36];
#pragma unroll
        for (int di = 0; di < 4; ++di)
#pragma unroll
          for (int qc = 0; qc < 2; ++qc)
            oacc[di][qc] += *(const f32x4*)(m_ + di * 8 + qc * 4);
        l_i[0] += m_[32];
        l_i[1] += m_[33];
      }
#pragma unroll
      for (int qc = 0; qc < 2; ++qc) {
        const float inv = 1.0f / l_i[qc];
        const int q = q0 + qc * 16 + ln;
        _Float16* orow = Ob + (size_t)(bidx * S_ + q) * DM + h * DH + quad * 4;
#pragma unroll
        for (int di = 0; di < 4; ++di) {
          f16x4 o4;
#pragma unroll
          for (int r = 0; r < 4; ++r)
            o4[r] = (_Float16)(oacc[di][qc][r] * inv);
          *(f16x4*)(orow + di * 16) = o4;
        }
      }
    }
    __syncthreads();   // mrg reused by member 2
  }
}

// ------------------------------- launcher ----------------------------------

extern "C" void kernel_launch(void* const* d_in, const int* in_sizes, int n_in,
                              void* d_out, int out_size, void* d_ws, size_t ws_size,
                              hipStream_t stream) {
  (void)in_sizes; (void)n_in; (void)out_size; (void)ws_size;
  const float* x  = (const float*)d_in[0];
  const float* Wq = (const float*)d_in[1];
  const float* bq = (const float*)d_in[2];
  const float* Wk = (const float*)d_in[3];
  const float* bk = (const float*)d_in[4];
  const float* Wv = (const float*)d_in[5];
  const float* bv = (const float*)d_in[6];
  const float* Wo = (const float*)d_in[7];
  const float* bo = (const float*)d_in[8];

  char* ws = (char*)d_ws;
  _Float16* xb  = (_Float16*)(ws);                      // 8 MB
  _Float16* wb  = (_Float16*)(ws + (8u << 20));         // 4 x 2 MB
  _Float16* qkv = (_Float16*)(ws + (16u << 20));        // QF,KF,VF 8 MB each
  _Float16* ob  = (_Float16*)(ws + (40u << 20));        // 8 MB

  cvt_x_kernel<<<dim3(4096), dim3(256), 0, stream>>>(x, xb);
  cvt_w_kernel<<<dim3(1024, 4), dim3(256), 0, stream>>>(Wq, Wk, Wv, Wo, wb);
  bias_fill_kernel<<<dim3(4096), dim3(256), 0, stream>>>(bo, (float*)d_out);
  gemm_qkv_kernel<<<dim3(8, 32, 3), dim3(256), 0, stream>>>(xb, wb, bq, bk, bv, qkv);
  attn_kernel<<<dim3(1024), dim3(256), 0, stream>>>(
      qkv, qkv + 4194304, qkv + 2 * 4194304, ob);
  gemm_out_kernel<<<dim3(8, 32, 2), dim3(256), 0, stream>>>(
      ob, wb + (size_t)3 * DM * DM, (float*)d_out);
}

// Round 9
// 207.304 us; speedup vs baseline: 2.2132x; 1.5353x over previous
//
#include <hip/hip_runtime.h>

// ---------------------------------------------------------------------------
// StandardMultiHeadAttention: B=2, S=2048, D=1024, H=16, Dh=64, causal.
// fp32->f16 convert -> QKV GEMM (epilogue scatters into MFMA-FRAGMENT-MAJOR
// layouts) -> flash attention (coalesced frag loads, S^T tiles, static-base
// softmax) -> bias-prefill + split-K output GEMM (fp32 atomics).
//
// Workspace (48 MB):
//   [0,8M)    xb : x f16 [4096,1024]
//   [8M,16M)  wb : Wq,Wk,Wv,Wo f16 (row=out, K-major)
//   [16M,24M) QF : Q frag-major (pre-scaled by 0.125*log2e)
//   [24M,32M) KF : K frag-major
//   [32M,40M) VF : V^T frag-major
//   [40M,48M) ob : attention output [B,S,1024] f16
//
// R8 post-mortem: still spilling — demand (64-reg KV dbuf + 16 qf + 48 AGPR
// + temps ~175) > (256,3) cap 170; compiler split 84/86, spilled the rest
// (FETCH 140MB WRITE 259MB). R9: SINGLE KV buffer (load K then V inside the
// tile; V's L2 latency hides behind the ~150cyc softmax VALU). Demand ~130
// << 170 -> no spill, 12 waves/CU; TLP (3 waves/SIMD) replaces reg-dbuf ILP.
// mrg stride 36->34 floats (2-way bank aliasing = free).
// ---------------------------------------------------------------------------

typedef _Float16 f16x8 __attribute__((ext_vector_type(8)));
typedef _Float16 f16x4 __attribute__((ext_vector_type(4)));
typedef _Float16 f16x2 __attribute__((ext_vector_type(2)));
typedef float f32x4 __attribute__((ext_vector_type(4)));

#define S_  2048
#define DM  1024
#define NH  16
#define DH  64

__device__ __forceinline__ void gload_lds16(const void* g, void* s) {
  __builtin_amdgcn_global_load_lds(
      (const __attribute__((address_space(1))) void*)g,
      (__attribute__((address_space(3))) void*)s, 16, 0, 0);
}

__device__ __forceinline__ f16x2 pkrtz(float a, float b) {
  return __builtin_bit_cast(f16x2, __builtin_amdgcn_cvt_pkrtz(a, b));
}

// ----------------------------- convert kernels -----------------------------

__global__ void cvt_x_kernel(const float* __restrict__ src,
                             _Float16* __restrict__ dst) {
  const int i = blockIdx.x * 256 + threadIdx.x;
  const float4 v = ((const float4*)src)[i];
  f16x4 h;
  h[0] = (_Float16)v.x; h[1] = (_Float16)v.y;
  h[2] = (_Float16)v.z; h[3] = (_Float16)v.w;
  ((f16x4*)dst)[i] = h;
}

__global__ void cvt_w_kernel(const float* __restrict__ w0,
                             const float* __restrict__ w1,
                             const float* __restrict__ w2,
                             const float* __restrict__ w3,
                             _Float16* __restrict__ dst) {
  const int y = blockIdx.y;
  const float* src = (y == 0) ? w0 : (y == 1) ? w1 : (y == 2) ? w2 : w3;
  const int i = blockIdx.x * 256 + threadIdx.x;
  const float4 v = ((const float4*)src)[i];
  f16x4 h;
  h[0] = (_Float16)v.x; h[1] = (_Float16)v.y;
  h[2] = (_Float16)v.z; h[3] = (_Float16)v.w;
  ((f16x4*)(dst + (size_t)y * (DM * DM)))[i] = h;
}

// d_out <- bias broadcast (split-K gemm_out atomically accumulates onto it)
__global__ void bias_fill_kernel(const float* __restrict__ bo,
                                 float* __restrict__ out) {
  const int i = blockIdx.x * 256 + threadIdx.x;   // float4 idx, 4096*256 total
  ((float4*)out)[i] = ((const float4*)bo)[i & 255];
}

// ------------------------------- GEMM core ---------------------------------

__device__ __forceinline__ void gemm_core(
    const _Float16* __restrict__ A, const _Float16* __restrict__ W,
    _Float16* As, _Float16* Ws, f32x4 acc[4][4], int m0, int n0,
    int kbeg, int kend)
{
  const int t = threadIdx.x;
  const int w = t >> 6, l = t & 63;
  const int quad = l >> 4, ln = l & 15;
  const int wm = (w >> 1) << 6, wn = (w & 1) << 6;
  const int srow = l >> 2, scol = (l & 3) << 3;

  for (int k0 = kbeg; k0 < kend; k0 += 32) {
#pragma unroll
    for (int i = 0; i < 2; ++i) {
      const int ra = w * 32 + i * 16;
      gload_lds16(&A[(size_t)(m0 + ra + srow) * DM + k0 + scol], &As[ra * 32]);
      gload_lds16(&W[(size_t)(n0 + ra + srow) * DM + k0 + scol], &Ws[ra * 32]);
    }
    __syncthreads();

    f16x8 af[4], bf[4];
#pragma unroll
    for (int mi = 0; mi < 4; ++mi)
      af[mi] = *(const f16x8*)&As[(wm + mi * 16 + ln) * 32 + quad * 8];
#pragma unroll
    for (int ni = 0; ni < 4; ++ni)
      bf[ni] = *(const f16x8*)&Ws[(wn + ni * 16 + ln) * 32 + quad * 8];
#pragma unroll
    for (int mi = 0; mi < 4; ++mi)
#pragma unroll
      for (int ni = 0; ni < 4; ++ni)
        acc[mi][ni] = __builtin_amdgcn_mfma_f32_16x16x32_f16(
            af[mi], bf[ni], acc[mi][ni], 0, 0, 0);
    __syncthreads();
  }
}

// z=0: Q (bias, *0.125*log2e, QF layout); z=1: K (bias, KF layout);
// z=2: V (bias, VF layout)
__global__ __launch_bounds__(256, 2) void gemm_qkv_kernel(
    const _Float16* __restrict__ xb, const _Float16* __restrict__ wb,
    const float* __restrict__ bq, const float* __restrict__ bk,
    const float* __restrict__ bv, _Float16* __restrict__ qkv)
{
  __shared__ _Float16 As[128 * 32];
  __shared__ _Float16 Ws[128 * 32];
  const int z = blockIdx.z;
  const _Float16* W = wb + (size_t)z * (DM * DM);
  const float* bias = (z == 0) ? bq : ((z == 1) ? bk : bv);
  _Float16* out = qkv + (size_t)z * 4194304;

  const f32x4 z4 = {0.f, 0.f, 0.f, 0.f};
  f32x4 acc[4][4];
#pragma unroll
  for (int mi = 0; mi < 4; ++mi)
#pragma unroll
    for (int ni = 0; ni < 4; ++ni) acc[mi][ni] = z4;

  const int m0 = blockIdx.y * 128, n0 = blockIdx.x * 128;
  gemm_core(xb, W, As, Ws, acc, m0, n0, 0, DM);

  const int t = threadIdx.x, w = t >> 6, l = t & 63;
  const int quad = l >> 4, ln = l & 15;
  const int wm = (w >> 1) << 6, wn = (w & 1) << 6;
  // fold 1/sqrt(Dh) * log2(e) into Q so attention uses exp2
  const float scale = (z == 0) ? 0.18033688f : 1.0f;

#pragma unroll
  for (int ni = 0; ni < 4; ++ni) {
    const int c = n0 + wn + ni * 16 + ln;
    const float bias_c = bias[c];
    const int h = c >> 6, d = c & 63;
#pragma unroll
    for (int mi = 0; mi < 4; ++mi) {
      const int mb = m0 + wm + mi * 16 + quad * 4;
#pragma unroll
      for (int r = 0; r < 4; ++r) {
        const int mg = mb + r;
        const int b = mg >> 11, s = mg & 2047;
        const int bh = b * NH + h;
        const float v = (acc[mi][ni][r] + bias_c) * scale;
        size_t idx;
        if (z == 2)
          idx = (size_t)bh * 131072 + (s >> 5) * 2048 + (d >> 4) * 512 +
                ((s >> 3) & 3) * 128 + (d & 15) * 8 + (s & 7);
        else
          idx = (size_t)bh * 131072 + (s >> 4) * 1024 + (d >> 5) * 512 +
                ((d >> 3) & 3) * 128 + (s & 15) * 8 + (d & 7);
        out[idx] = (_Float16)v;
      }
    }
  }
}

// split-K=2: z = K-half; atomically accumulates onto bias-prefilled out.
__global__ __launch_bounds__(256, 2) void gemm_out_kernel(
    const _Float16* __restrict__ ob, const _Float16* __restrict__ wo,
    float* __restrict__ out)
{
  __shared__ _Float16 As[128 * 32];
  __shared__ _Float16 Ws[128 * 32];
  const f32x4 z4 = {0.f, 0.f, 0.f, 0.f};
  f32x4 acc[4][4];
#pragma unroll
  for (int mi = 0; mi < 4; ++mi)
#pragma unroll
    for (int ni = 0; ni < 4; ++ni) acc[mi][ni] = z4;

  const int m0 = blockIdx.y * 128, n0 = blockIdx.x * 128;
  const int kbeg = blockIdx.z * 512;
  gemm_core(ob, wo, As, Ws, acc, m0, n0, kbeg, kbeg + 512);

  const int t = threadIdx.x, w = t >> 6, l = t & 63;
  const int quad = l >> 4, ln = l & 15;
  const int wm = (w >> 1) << 6, wn = (w & 1) << 6;

#pragma unroll
  for (int ni = 0; ni < 4; ++ni) {
    const int c = n0 + wn + ni * 16 + ln;
#pragma unroll
    for (int mi = 0; mi < 4; ++mi) {
      const int mb = m0 + wm + mi * 16 + quad * 4;
#pragma unroll
      for (int r = 0; r < 4; ++r)
        atomicAdd(&out[(size_t)(mb + r) * DM + c], acc[mi][ni][r]);
    }
  }
}

// ---------------------------- flash attention ------------------------------
// 1024 blocks x 4 waves (12 waves/CU at 3 blocks/CU). Block = (head bh,
// pair p): wave w takes kv tiles t == w (mod 4) for q-tiles {63-p, p}
// (65 tiles/pair, ~16/wave, all waves equal; disjoint tiles -> KV traffic
// unchanged). SINGLE KV reg buffer: K loads -> S MFMAs; V loads issued
// with K but only waited after softmax (latency hidden by exp VALU work).
// Partial (O,l) merged via LDS. l quad-reduction deferred.

template <bool DIAG>
__device__ __forceinline__ void compute_tile(
    const _Float16* __restrict__ kb_, const _Float16* __restrict__ vb_,
    int t, const f16x8 (&qf)[2][2], f32x4 (&oacc)[4][2],
    float (&l_i)[2], _Float16* Ps, int quad, int ln, int l)
{
  f16x8 kf[4], vf[4];
#pragma unroll
  for (int i = 0; i < 4; ++i)
    kf[i] = *(const f16x8*)(kb_ + (size_t)(t * 4 + i) * 512 + l * 8);
#pragma unroll
  for (int i = 0; i < 4; ++i)
    vf[i] = *(const f16x8*)(vb_ + (size_t)(t * 4 + i) * 512 + l * 8);

  const f32x4 z4 = {0.f, 0.f, 0.f, 0.f};
  f32x4 sacc[2][2];
#pragma unroll
  for (int mi = 0; mi < 2; ++mi)
#pragma unroll
    for (int qc = 0; qc < 2; ++qc) sacc[mi][qc] = z4;

  // S^T tile: A = K frag (m=kv), B = Q frag (n=q)
#pragma unroll
  for (int ks = 0; ks < 2; ++ks)
#pragma unroll
    for (int mi = 0; mi < 2; ++mi)
#pragma unroll
      for (int qc = 0; qc < 2; ++qc)
        sacc[mi][qc] = __builtin_amdgcn_mfma_f32_16x16x32_f16(
            kf[mi * 2 + ks], qf[qc][ks], sacc[mi][qc], 0, 0, 0);

  // static-base softmax: p = 2^s (Q pre-scaled by 0.125*log2e);
  // l_i accumulates per-lane (own-quad rows); quad reduction deferred.
  const int sw = (ln & 3) << 1;   // even XOR key: keeps 16B read alignment
#pragma unroll
  for (int qc = 0; qc < 2; ++qc) {
    float rs = 0.f;
#pragma unroll
    for (int mi = 0; mi < 2; ++mi) {
      float p[4];
#pragma unroll
      for (int r = 0; r < 4; ++r) {
        p[r] = __builtin_amdgcn_exp2f(sacc[mi][qc][r]);
        if (DIAG && (mi * 16 + quad * 4 + r > qc * 16 + ln)) p[r] = 0.f;
        rs += p[r];
      }
      const f16x2 lo = pkrtz(p[0], p[1]);
      const f16x2 hi = pkrtz(p[2], p[3]);
      const f16x4 pk = __builtin_shufflevector(lo, hi, 0, 1, 2, 3);
      const int g = (mi * 4 + quad) ^ sw;          // 8B granule, swizzled
      *(f16x4*)&Ps[(qc * 16 + ln) * 40 + g * 4] = pk;
    }
    l_i[qc] += rs;
  }

  // P^T B-frags (row q=ln, kv contiguous) — wave-private, no barrier
  f16x8 pb[2];
#pragma unroll
  for (int qc = 0; qc < 2; ++qc) {
    const int g2 = (quad * 2) ^ sw;                // even -> pair contiguous
    pb[qc] = *(const f16x8*)&Ps[(qc * 16 + ln) * 40 + g2 * 4];
  }

  // O^T += V^T * P^T
#pragma unroll
  for (int di = 0; di < 4; ++di)
#pragma unroll
    for (int qc = 0; qc < 2; ++qc)
      oacc[di][qc] = __builtin_amdgcn_mfma_f32_16x16x32_f16(
          vf[di], pb[qc], oacc[di][qc], 0, 0, 0);
}

__global__ __launch_bounds__(256, 3) void attn_kernel(
    const _Float16* __restrict__ QF, const _Float16* __restrict__ KF,
    const _Float16* __restrict__ VF, _Float16* __restrict__ Ob)
{
  __shared__ _Float16 Ps[4 * 32 * 40];   // per-wave P transpose buffers
  __shared__ float mrg[3 * 64 * 34];     // cross-wave (O,l) merge (2l mod 32)

  // block -> (bh, pair): XCD x = i&7 sees 4 heads (2MB KV <= 4MB L2/XCD)
  const int i = blockIdx.x;
  const int bh = ((i & 7) << 2) | ((i >> 3) & 3);
  const int p = i >> 5;                  // pair index 0..31

  const int tid = threadIdx.x;
  const int w = tid >> 6, l = tid & 63;  // w = kv residue mod 4
  const int quad = l >> 4, ln = l & 15;

  const _Float16* qb_ = QF + (size_t)bh * 131072;
  const _Float16* kb_ = KF + (size_t)bh * 131072;
  const _Float16* vb_ = VF + (size_t)bh * 131072;
  _Float16* psw = Ps + w * (32 * 40);
  const int bidx = bh >> 4, h = bh & 15;

  const f32x4 z4 = {0.f, 0.f, 0.f, 0.f};

#pragma unroll
  for (int mem = 0; mem < 2; ++mem) {
    const int qw = (mem == 0) ? (63 - p) : p;
    const int q0 = qw << 5;

    f16x8 qf[2][2];
#pragma unroll
    for (int qc = 0; qc < 2; ++qc)
#pragma unroll
      for (int ks = 0; ks < 2; ++ks)
        qf[qc][ks] = *(const f16x8*)
            (qb_ + (size_t)((2 * qw + qc) * 2 + ks) * 512 + l * 8);

    f32x4 oacc[4][2];
#pragma unroll
    for (int di = 0; di < 4; ++di)
#pragma unroll
      for (int qc = 0; qc < 2; ++qc) oacc[di][qc] = z4;
    float l_i[2] = {0.f, 0.f};

    // kv tiles t = w, w+4, ..., <= qw ; tile t==qw is the diagonal
    int t = w;
    for (; t < qw; t += 4)
      compute_tile<false>(kb_, vb_, t, qf, oacc, l_i, psw, quad, ln, l);
    if (t == qw)
      compute_tile<true>(kb_, vb_, t, qf, oacc, l_i, psw, quad, ln, l);

    // deferred quad-reduction of l partials (2 shuffles per qc, once)
#pragma unroll
    for (int qc = 0; qc < 2; ++qc) {
      float s = l_i[qc];
      s += __shfl_xor(s, 16);
      s += __shfl_xor(s, 32);
      l_i[qc] = s;
    }

    // merge partials: waves 1..3 -> LDS, barrier, wave0 adds + writes O
    if (w != 0) {
      float* m_ = &mrg[((w - 1) * 64 + l) * 34];
#pragma unroll
      for (int di = 0; di < 4; ++di)
#pragma unroll
        for (int qc = 0; qc < 2; ++qc)
          *(f32x4*)(m_ + di * 8 + qc * 4) = oacc[di][qc];
      m_[32] = l_i[0];
      m_[33] = l_i[1];
    }
    __syncthreads();
    if (w == 0) {
#pragma unroll
      for (int ww = 0; ww < 3; ++ww) {
        const float* m_ = &mrg[(ww * 64 + l) * 34];
#pragma unroll
        for (int di = 0; di < 4; ++di)
#pragma unroll
          for (int qc = 0; qc < 2; ++qc)
            oacc[di][qc] += *(const f32x4*)(m_ + di * 8 + qc * 4);
        l_i[0] += m_[32];
        l_i[1] += m_[33];
      }
#pragma unroll
      for (int qc = 0; qc < 2; ++qc) {
        const float inv = 1.0f / l_i[qc];
        const int q = q0 + qc * 16 + ln;
        _Float16* orow = Ob + (size_t)(bidx * S_ + q) * DM + h * DH + quad * 4;
#pragma unroll
        for (int di = 0; di < 4; ++di) {
          f16x4 o4;
#pragma unroll
          for (int r = 0; r < 4; ++r)
            o4[r] = (_Float16)(oacc[di][qc][r] * inv);
          *(f16x4*)(orow + di * 16) = o4;
        }
      }
    }
    __syncthreads();   // mrg reused by member 2
  }
}

// ------------------------------- launcher ----------------------------------

extern "C" void kernel_launch(void* const* d_in, const int* in_sizes, int n_in,
                              void* d_out, int out_size, void* d_ws, size_t ws_size,
                              hipStream_t stream) {
  (void)in_sizes; (void)n_in; (void)out_size; (void)ws_size;
  const float* x  = (const float*)d_in[0];
  const float* Wq = (const float*)d_in[1];
  const float* bq = (const float*)d_in[2];
  const float* Wk = (const float*)d_in[3];
  const float* bk = (const float*)d_in[4];
  const float* Wv = (const float*)d_in[5];
  const float* bv = (const float*)d_in[6];
  const float* Wo = (const float*)d_in[7];
  const float* bo = (const float*)d_in[8];

  char* ws = (char*)d_ws;
  _Float16* xb  = (_Float16*)(ws);                      // 8 MB
  _Float16* wb  = (_Float16*)(ws + (8u << 20));         // 4 x 2 MB
  _Float16* qkv = (_Float16*)(ws + (16u << 20));        // QF,KF,VF 8 MB each
  _Float16* ob  = (_Float16*)(ws + (40u << 20));        // 8 MB

  cvt_x_kernel<<<dim3(4096), dim3(256), 0, stream>>>(x, xb);
  cvt_w_kernel<<<dim3(1024, 4), dim3(256), 0, stream>>>(Wq, Wk, Wv, Wo, wb);
  bias_fill_kernel<<<dim3(4096), dim3(256), 0, stream>>>(bo, (float*)d_out);
  gemm_qkv_kernel<<<dim3(8, 32, 3), dim3(256), 0, stream>>>(xb, wb, bq, bk, bv, qkv);
  attn_kernel<<<dim3(1024), dim3(256), 0, stream>>>(
      qkv, qkv + 4194304, qkv + 2 * 4194304, ob);
  gemm_out_kernel<<<dim3(8, 32, 2), dim3(256), 0, stream>>>(
      ob, wb + (size_t)3 * DM * DM, (float*)d_out);
}

// Round 10
// 181.639 us; speedup vs baseline: 2.5260x; 1.1413x over previous
//
#include <hip/hip_runtime.h>

// ---------------------------------------------------------------------------
// StandardMultiHeadAttention: B=2, S=2048, D=1024, H=16, Dh=64, causal.
// fp32->f16 convert -> QKV GEMM (BK=64, frag-major epilogue) -> flash
// attention (coalesced frag loads, S^T tiles, static-base softmax) ->
// output GEMM (128x64 tiles, direct fp32 write + bias).
//
// Workspace (48 MB):
//   [0,8M)    xb : x f16 [4096,1024]
//   [8M,16M)  wb : Wq,Wk,Wv,Wo f16 (row=out, K-major)
//   [16M,24M) QF : Q frag-major (pre-scaled by 0.125*log2e)
//   [24M,32M) KF : K frag-major
//   [32M,40M) VF : V^T frag-major
//   [40M,48M) ob : attention output [B,S,1024] f16
//
// R9 post-mortem: split-K atomics regressed gemm_out (~+13us); qkv stuck at
// 43.5us (MfmaUtil 22%, all pipes idle -> barrier-drain bound, 16 MFMA/wave
// per barrier). R10: qkv BK=64 via TWO stride-32 LDS slabs (padding breaks
// global_load_lds lane x 16 dest; two slabs keep the conflict-modest read
// pattern) -> 32 MFMA/barrier, half the drains. gemm_out back to direct
// write+bias, 128x64 tiles (512 blocks = 2/CU). attn unchanged (control).
// ---------------------------------------------------------------------------

typedef _Float16 f16x8 __attribute__((ext_vector_type(8)));
typedef _Float16 f16x4 __attribute__((ext_vector_type(4)));
typedef _Float16 f16x2 __attribute__((ext_vector_type(2)));
typedef float f32x4 __attribute__((ext_vector_type(4)));

#define S_  2048
#define DM  1024
#define NH  16
#define DH  64

__device__ __forceinline__ void gload_lds16(const void* g, void* s) {
  __builtin_amdgcn_global_load_lds(
      (const __attribute__((address_space(1))) void*)g,
      (__attribute__((address_space(3))) void*)s, 16, 0, 0);
}

__device__ __forceinline__ f16x2 pkrtz(float a, float b) {
  return __builtin_bit_cast(f16x2, __builtin_amdgcn_cvt_pkrtz(a, b));
}

// ----------------------------- convert kernels -----------------------------

__global__ void cvt_x_kernel(const float* __restrict__ src,
                             _Float16* __restrict__ dst) {
  const int i = blockIdx.x * 256 + threadIdx.x;
  const float4 v = ((const float4*)src)[i];
  f16x4 h;
  h[0] = (_Float16)v.x; h[1] = (_Float16)v.y;
  h[2] = (_Float16)v.z; h[3] = (_Float16)v.w;
  ((f16x4*)dst)[i] = h;
}

__global__ void cvt_w_kernel(const float* __restrict__ w0,
                             const float* __restrict__ w1,
                             const float* __restrict__ w2,
                             const float* __restrict__ w3,
                             _Float16* __restrict__ dst) {
  const int y = blockIdx.y;
  const float* src = (y == 0) ? w0 : (y == 1) ? w1 : (y == 2) ? w2 : w3;
  const int i = blockIdx.x * 256 + threadIdx.x;
  const float4 v = ((const float4*)src)[i];
  f16x4 h;
  h[0] = (_Float16)v.x; h[1] = (_Float16)v.y;
  h[2] = (_Float16)v.z; h[3] = (_Float16)v.w;
  ((f16x4*)(dst + (size_t)y * (DM * DM)))[i] = h;
}

// ------------------------- QKV GEMM (BK=64, 2 slabs) ------------------------
// z=0: Q (bias, *0.125*log2e, QF layout); z=1: K (KF); z=2: V (VF)

__global__ __launch_bounds__(256, 2) void gemm_qkv_kernel(
    const _Float16* __restrict__ xb, const _Float16* __restrict__ wb,
    const float* __restrict__ bq, const float* __restrict__ bk,
    const float* __restrict__ bv, _Float16* __restrict__ qkv)
{
  __shared__ _Float16 As[2][128 * 32];   // slab h covers k in [k0+32h, k0+32h+32)
  __shared__ _Float16 Ws[2][128 * 32];
  const int z = blockIdx.z;
  const _Float16* W = wb + (size_t)z * (DM * DM);
  const float* bias = (z == 0) ? bq : ((z == 1) ? bk : bv);
  _Float16* out = qkv + (size_t)z * 4194304;

  const f32x4 z4 = {0.f, 0.f, 0.f, 0.f};
  f32x4 acc[4][4];
#pragma unroll
  for (int mi = 0; mi < 4; ++mi)
#pragma unroll
    for (int ni = 0; ni < 4; ++ni) acc[mi][ni] = z4;

  const int m0 = blockIdx.y * 128, n0 = blockIdx.x * 128;
  const int t = threadIdx.x;
  const int w = t >> 6, l = t & 63;
  const int quad = l >> 4, ln = l & 15;
  const int wm = (w >> 1) << 6, wn = (w & 1) << 6;
  const int srow = l >> 2, scol = (l & 3) << 3;

  for (int k0 = 0; k0 < DM; k0 += 64) {
#pragma unroll
    for (int h = 0; h < 2; ++h)
#pragma unroll
      for (int i = 0; i < 2; ++i) {
        const int ra = w * 32 + i * 16;
        gload_lds16(&xb[(size_t)(m0 + ra + srow) * DM + k0 + h * 32 + scol],
                    &As[h][ra * 32]);
        gload_lds16(&W[(size_t)(n0 + ra + srow) * DM + k0 + h * 32 + scol],
                    &Ws[h][ra * 32]);
      }
    __syncthreads();

#pragma unroll
    for (int h = 0; h < 2; ++h) {
      f16x8 af[4], bf[4];
#pragma unroll
      for (int mi = 0; mi < 4; ++mi)
        af[mi] = *(const f16x8*)&As[h][(wm + mi * 16 + ln) * 32 + quad * 8];
#pragma unroll
      for (int ni = 0; ni < 4; ++ni)
        bf[ni] = *(const f16x8*)&Ws[h][(wn + ni * 16 + ln) * 32 + quad * 8];
#pragma unroll
      for (int mi = 0; mi < 4; ++mi)
#pragma unroll
        for (int ni = 0; ni < 4; ++ni)
          acc[mi][ni] = __builtin_amdgcn_mfma_f32_16x16x32_f16(
              af[mi], bf[ni], acc[mi][ni], 0, 0, 0);
    }
    __syncthreads();
  }

  // fold 1/sqrt(Dh) * log2(e) into Q so attention uses exp2
  const float scale = (z == 0) ? 0.18033688f : 1.0f;

#pragma unroll
  for (int ni = 0; ni < 4; ++ni) {
    const int c = n0 + wn + ni * 16 + ln;
    const float bias_c = bias[c];
    const int h = c >> 6, d = c & 63;
#pragma unroll
    for (int mi = 0; mi < 4; ++mi) {
      const int mb = m0 + wm + mi * 16 + quad * 4;
#pragma unroll
      for (int r = 0; r < 4; ++r) {
        const int mg = mb + r;
        const int b = mg >> 11, s = mg & 2047;
        const int bh = b * NH + h;
        const float v = (acc[mi][ni][r] + bias_c) * scale;
        size_t idx;
        if (z == 2)
          idx = (size_t)bh * 131072 + (s >> 5) * 2048 + (d >> 4) * 512 +
                ((s >> 3) & 3) * 128 + (d & 15) * 8 + (s & 7);
        else
          idx = (size_t)bh * 131072 + (s >> 4) * 1024 + (d >> 5) * 512 +
                ((d >> 3) & 3) * 128 + (s & 15) * 8 + (d & 7);
        out[idx] = (_Float16)v;
      }
    }
  }
}

// ------------------- output GEMM (128x64 tile, direct write) ----------------

__global__ __launch_bounds__(256, 2) void gemm_out_kernel(
    const _Float16* __restrict__ ob, const _Float16* __restrict__ wo,
    const float* __restrict__ bo, float* __restrict__ out)
{
  __shared__ _Float16 As[128 * 32];
  __shared__ _Float16 Ws[64 * 32];
  const f32x4 z4 = {0.f, 0.f, 0.f, 0.f};
  f32x4 acc[2][4];
#pragma unroll
  for (int mi = 0; mi < 2; ++mi)
#pragma unroll
    for (int ni = 0; ni < 4; ++ni) acc[mi][ni] = z4;

  const int m0 = blockIdx.y * 128, n0 = blockIdx.x * 64;
  const int t = threadIdx.x;
  const int w = t >> 6, l = t & 63;
  const int quad = l >> 4, ln = l & 15;
  const int srow = l >> 2, scol = (l & 3) << 3;

  for (int k0 = 0; k0 < DM; k0 += 32) {
#pragma unroll
    for (int i = 0; i < 2; ++i) {
      const int ra = w * 32 + i * 16;
      gload_lds16(&ob[(size_t)(m0 + ra + srow) * DM + k0 + scol], &As[ra * 32]);
    }
    gload_lds16(&wo[(size_t)(n0 + w * 16 + srow) * DM + k0 + scol],
                &Ws[w * 16 * 32]);
    __syncthreads();

    f16x8 af[2], bf[4];
#pragma unroll
    for (int mi = 0; mi < 2; ++mi)
      af[mi] = *(const f16x8*)&As[(w * 32 + mi * 16 + ln) * 32 + quad * 8];
#pragma unroll
    for (int ni = 0; ni < 4; ++ni)
      bf[ni] = *(const f16x8*)&Ws[(ni * 16 + ln) * 32 + quad * 8];
#pragma unroll
    for (int mi = 0; mi < 2; ++mi)
#pragma unroll
      for (int ni = 0; ni < 4; ++ni)
        acc[mi][ni] = __builtin_amdgcn_mfma_f32_16x16x32_f16(
            af[mi], bf[ni], acc[mi][ni], 0, 0, 0);
    __syncthreads();
  }

#pragma unroll
  for (int ni = 0; ni < 4; ++ni) {
    const int c = n0 + ni * 16 + ln;
    const float bias_c = bo[c];
#pragma unroll
    for (int mi = 0; mi < 2; ++mi) {
      const int mb = m0 + w * 32 + mi * 16 + quad * 4;
#pragma unroll
      for (int r = 0; r < 4; ++r)
        out[(size_t)(mb + r) * DM + c] = acc[mi][ni][r] + bias_c;
    }
  }
}

// ---------------------------- flash attention ------------------------------
// 1024 blocks x 4 waves. Block = (head bh, pair p): wave w takes kv tiles
// t == w (mod 4) for q-tiles {63-p, p}. Single KV reg buffer; partial (O,l)
// merged via LDS; l quad-reduction deferred. (unchanged from R9)

template <bool DIAG>
__device__ __forceinline__ void compute_tile(
    const _Float16* __restrict__ kb_, const _Float16* __restrict__ vb_,
    int t, const f16x8 (&qf)[2][2], f32x4 (&oacc)[4][2],
    float (&l_i)[2], _Float16* Ps, int quad, int ln, int l)
{
  f16x8 kf[4], vf[4];
#pragma unroll
  for (int i = 0; i < 4; ++i)
    kf[i] = *(const f16x8*)(kb_ + (size_t)(t * 4 + i) * 512 + l * 8);
#pragma unroll
  for (int i = 0; i < 4; ++i)
    vf[i] = *(const f16x8*)(vb_ + (size_t)(t * 4 + i) * 512 + l * 8);

  const f32x4 z4 = {0.f, 0.f, 0.f, 0.f};
  f32x4 sacc[2][2];
#pragma unroll
  for (int mi = 0; mi < 2; ++mi)
#pragma unroll
    for (int qc = 0; qc < 2; ++qc) sacc[mi][qc] = z4;

#pragma unroll
  for (int ks = 0; ks < 2; ++ks)
#pragma unroll
    for (int mi = 0; mi < 2; ++mi)
#pragma unroll
      for (int qc = 0; qc < 2; ++qc)
        sacc[mi][qc] = __builtin_amdgcn_mfma_f32_16x16x32_f16(
            kf[mi * 2 + ks], qf[qc][ks], sacc[mi][qc], 0, 0, 0);

  const int sw = (ln & 3) << 1;
#pragma unroll
  for (int qc = 0; qc < 2; ++qc) {
    float rs = 0.f;
#pragma unroll
    for (int mi = 0; mi < 2; ++mi) {
      float p[4];
#pragma unroll
      for (int r = 0; r < 4; ++r) {
        p[r] = __builtin_amdgcn_exp2f(sacc[mi][qc][r]);
        if (DIAG && (mi * 16 + quad * 4 + r > qc * 16 + ln)) p[r] = 0.f;
        rs += p[r];
      }
      const f16x2 lo = pkrtz(p[0], p[1]);
      const f16x2 hi = pkrtz(p[2], p[3]);
      const f16x4 pk = __builtin_shufflevector(lo, hi, 0, 1, 2, 3);
      const int g = (mi * 4 + quad) ^ sw;
      *(f16x4*)&Ps[(qc * 16 + ln) * 40 + g * 4] = pk;
    }
    l_i[qc] += rs;
  }

  f16x8 pb[2];
#pragma unroll
  for (int qc = 0; qc < 2; ++qc) {
    const int g2 = (quad * 2) ^ sw;
    pb[qc] = *(const f16x8*)&Ps[(qc * 16 + ln) * 40 + g2 * 4];
  }

#pragma unroll
  for (int di = 0; di < 4; ++di)
#pragma unroll
    for (int qc = 0; qc < 2; ++qc)
      oacc[di][qc] = __builtin_amdgcn_mfma_f32_16x16x32_f16(
          vf[di], pb[qc], oacc[di][qc], 0, 0, 0);
}

__global__ __launch_bounds__(256, 3) void attn_kernel(
    const _Float16* __restrict__ QF, const _Float16* __restrict__ KF,
    const _Float16* __restrict__ VF, _Float16* __restrict__ Ob)
{
  __shared__ _Float16 Ps[4 * 32 * 40];
  __shared__ float mrg[3 * 64 * 34];

  const int i = blockIdx.x;
  const int bh = ((i & 7) << 2) | ((i >> 3) & 3);
  const int p = i >> 5;

  const int tid = threadIdx.x;
  const int w = tid >> 6, l = tid & 63;
  const int quad = l >> 4, ln = l & 15;

  const _Float16* qb_ = QF + (size_t)bh * 131072;
  const _Float16* kb_ = KF + (size_t)bh * 131072;
  const _Float16* vb_ = VF + (size_t)bh * 131072;
  _Float16* psw = Ps + w * (32 * 40);
  const int bidx = bh >> 4, h = bh & 15;

  const f32x4 z4 = {0.f, 0.f, 0.f, 0.f};

#pragma unroll
  for (int mem = 0; mem < 2; ++mem) {
    const int qw = (mem == 0) ? (63 - p) : p;
    const int q0 = qw << 5;

    f16x8 qf[2][2];
#pragma unroll
    for (int qc = 0; qc < 2; ++qc)
#pragma unroll
      for (int ks = 0; ks < 2; ++ks)
        qf[qc][ks] = *(const f16x8*)
            (qb_ + (size_t)((2 * qw + qc) * 2 + ks) * 512 + l * 8);

    f32x4 oacc[4][2];
#pragma unroll
    for (int di = 0; di < 4; ++di)
#pragma unroll
      for (int qc = 0; qc < 2; ++qc) oacc[di][qc] = z4;
    float l_i[2] = {0.f, 0.f};

    int t = w;
    for (; t < qw; t += 4)
      compute_tile<false>(kb_, vb_, t, qf, oacc, l_i, psw, quad, ln, l);
    if (t == qw)
      compute_tile<true>(kb_, vb_, t, qf, oacc, l_i, psw, quad, ln, l);

#pragma unroll
    for (int qc = 0; qc < 2; ++qc) {
      float s = l_i[qc];
      s += __shfl_xor(s, 16);
      s += __shfl_xor(s, 32);
      l_i[qc] = s;
    }

    if (w != 0) {
      float* m_ = &mrg[((w - 1) * 64 + l) * 34];
#pragma unroll
      for (int di = 0; di < 4; ++di)
#pragma unroll
        for (int qc = 0; qc < 2; ++qc)
          *(f32x4*)(m_ + di * 8 + qc * 4) = oacc[di][qc];
      m_[32] = l_i[0];
      m_[33] = l_i[1];
    }
    __syncthreads();
    if (w == 0) {
#pragma unroll
      for (int ww = 0; ww < 3; ++ww) {
        const float* m_ = &mrg[(ww * 64 + l) * 34];
#pragma unroll
        for (int di = 0; di < 4; ++di)
#pragma unroll
          for (int qc = 0; qc < 2; ++qc)
            oacc[di][qc] += *(const f32x4*)(m_ + di * 8 + qc * 4);
        l_i[0] += m_[32];
        l_i[1] += m_[33];
      }
#pragma unroll
      for (int qc = 0; qc < 2; ++qc) {
        const float inv = 1.0f / l_i[qc];
        const int q = q0 + qc * 16 + ln;
        _Float16* orow = Ob + (size_t)(bidx * S_ + q) * DM + h * DH + quad * 4;
#pragma unroll
        for (int di = 0; di < 4; ++di) {
          f16x4 o4;
#pragma unroll
          for (int r = 0; r < 4; ++r)
            o4[r] = (_Float16)(oacc[di][qc][r] * inv);
          *(f16x4*)(orow + di * 16) = o4;
        }
      }
    }
    __syncthreads();
  }
}

// ------------------------------- launcher ----------------------------------

extern "C" void kernel_launch(void* const* d_in, const int* in_sizes, int n_in,
                              void* d_out, int out_size, void* d_ws, size_t ws_size,
                              hipStream_t stream) {
  (void)in_sizes; (void)n_in; (void)out_size; (void)ws_size;
  const float* x  = (const float*)d_in[0];
  const float* Wq = (const float*)d_in[1];
  const float* bq = (const float*)d_in[2];
  const float* Wk = (const float*)d_in[3];
  const float* bk = (const float*)d_in[4];
  const float* Wv = (const float*)d_in[5];
  const float* bv = (const float*)d_in[6];
  const float* Wo = (const float*)d_in[7];
  const float* bo = (const float*)d_in[8];

  char* ws = (char*)d_ws;
  _Float16* xb  = (_Float16*)(ws);                      // 8 MB
  _Float16* wb  = (_Float16*)(ws + (8u << 20));         // 4 x 2 MB
  _Float16* qkv = (_Float16*)(ws + (16u << 20));        // QF,KF,VF 8 MB each
  _Float16* ob  = (_Float16*)(ws + (40u << 20));        // 8 MB

  cvt_x_kernel<<<dim3(4096), dim3(256), 0, stream>>>(x, xb);
  cvt_w_kernel<<<dim3(1024, 4), dim3(256), 0, stream>>>(Wq, Wk, Wv, Wo, wb);
  gemm_qkv_kernel<<<dim3(8, 32, 3), dim3(256), 0, stream>>>(xb, wb, bq, bk, bv, qkv);
  attn_kernel<<<dim3(1024), dim3(256), 0, stream>>>(
      qkv, qkv + 4194304, qkv + 2 * 4194304, ob);
  gemm_out_kernel<<<dim3(16, 32), dim3(256), 0, stream>>>(
      ob, wb + (size_t)3 * DM * DM, bo, (float*)d_out);
}

// Round 11
// 180.680 us; speedup vs baseline: 2.5394x; 1.0053x over previous
//
#include <hip/hip_runtime.h>

// ---------------------------------------------------------------------------
// StandardMultiHeadAttention: B=2, S=2048, D=1024, H=16, Dh=64, causal.
// fp32->f16 convert (single kernel) -> QKV GEMM (BK=64, frag-major epilogue)
// -> flash attention (K-prefetch pipeline, S^T tiles, static-base softmax)
// -> output GEMM (BK=64, 128x64 tiles, direct fp32 write + bias).
//
// Workspace (48 MB):
//   [0,8M)    xb : x f16 [4096,1024]
//   [8M,16M)  wb : Wq,Wk,Wv,Wo f16 (row=out, K-major)
//   [16M,24M) QF : Q frag-major (pre-scaled by 0.125*log2e)
//   [24M,32M) KF : K frag-major
//   [32M,40M) VF : V^T frag-major
//   [40M,48M) ob : attention output [B,S,1024] f16
//
// R10 post-mortem: qkv BK=64 + direct gemm_out => 181.6us; all kernels now
// below the 42us fill floor (no counters). R11: (1) attn K-prefetch pipeline
// (+16 VGPR only, ~150 < 170 cap -- not the 32-reg dbuf that spilled R7/R8):
// S-MFMA operands land during prior tile's softmax+PV; (2) gemm_out BK=64
// two-slab (16 MFMA/barrier); (3) cvt_x+cvt_w merged into one launch.
// ---------------------------------------------------------------------------

typedef _Float16 f16x8 __attribute__((ext_vector_type(8)));
typedef _Float16 f16x4 __attribute__((ext_vector_type(4)));
typedef _Float16 f16x2 __attribute__((ext_vector_type(2)));
typedef float f32x4 __attribute__((ext_vector_type(4)));

#define S_  2048
#define DM  1024
#define NH  16
#define DH  64

__device__ __forceinline__ void gload_lds16(const void* g, void* s) {
  __builtin_amdgcn_global_load_lds(
      (const __attribute__((address_space(1))) void*)g,
      (__attribute__((address_space(3))) void*)s, 16, 0, 0);
}

__device__ __forceinline__ f16x2 pkrtz(float a, float b) {
  return __builtin_bit_cast(f16x2, __builtin_amdgcn_cvt_pkrtz(a, b));
}

// ----------------------------- convert kernel ------------------------------
// blocks [0,4096): x -> xb ; blocks [4096,8192): Wq..Wo -> wb

__global__ void cvt_all_kernel(const float* __restrict__ x,
                               const float* __restrict__ w0,
                               const float* __restrict__ w1,
                               const float* __restrict__ w2,
                               const float* __restrict__ w3,
                               _Float16* __restrict__ xb,
                               _Float16* __restrict__ wb) {
  const int bid = blockIdx.x;
  const float* src;
  _Float16* dst;
  int idx;
  if (bid < 4096) {
    src = x; dst = xb; idx = bid * 256 + threadIdx.x;
  } else {
    const int j = bid - 4096;
    const int y = j >> 10;
    src = (y == 0) ? w0 : (y == 1) ? w1 : (y == 2) ? w2 : w3;
    dst = wb + (size_t)y * (DM * DM);
    idx = (j & 1023) * 256 + threadIdx.x;
  }
  const float4 v = ((const float4*)src)[idx];
  f16x4 h;
  h[0] = (_Float16)v.x; h[1] = (_Float16)v.y;
  h[2] = (_Float16)v.z; h[3] = (_Float16)v.w;
  ((f16x4*)dst)[idx] = h;
}

// ------------------------- QKV GEMM (BK=64, 2 slabs) ------------------------
// z=0: Q (bias, *0.125*log2e, QF layout); z=1: K (KF); z=2: V (VF)

__global__ __launch_bounds__(256, 2) void gemm_qkv_kernel(
    const _Float16* __restrict__ xb, const _Float16* __restrict__ wb,
    const float* __restrict__ bq, const float* __restrict__ bk,
    const float* __restrict__ bv, _Float16* __restrict__ qkv)
{
  __shared__ _Float16 As[2][128 * 32];   // slab h: k in [k0+32h, k0+32h+32)
  __shared__ _Float16 Ws[2][128 * 32];
  const int z = blockIdx.z;
  const _Float16* W = wb + (size_t)z * (DM * DM);
  const float* bias = (z == 0) ? bq : ((z == 1) ? bk : bv);
  _Float16* out = qkv + (size_t)z * 4194304;

  const f32x4 z4 = {0.f, 0.f, 0.f, 0.f};
  f32x4 acc[4][4];
#pragma unroll
  for (int mi = 0; mi < 4; ++mi)
#pragma unroll
    for (int ni = 0; ni < 4; ++ni) acc[mi][ni] = z4;

  const int m0 = blockIdx.y * 128, n0 = blockIdx.x * 128;
  const int t = threadIdx.x;
  const int w = t >> 6, l = t & 63;
  const int quad = l >> 4, ln = l & 15;
  const int wm = (w >> 1) << 6, wn = (w & 1) << 6;
  const int srow = l >> 2, scol = (l & 3) << 3;

  for (int k0 = 0; k0 < DM; k0 += 64) {
#pragma unroll
    for (int h = 0; h < 2; ++h)
#pragma unroll
      for (int i = 0; i < 2; ++i) {
        const int ra = w * 32 + i * 16;
        gload_lds16(&xb[(size_t)(m0 + ra + srow) * DM + k0 + h * 32 + scol],
                    &As[h][ra * 32]);
        gload_lds16(&W[(size_t)(n0 + ra + srow) * DM + k0 + h * 32 + scol],
                    &Ws[h][ra * 32]);
      }
    __syncthreads();

#pragma unroll
    for (int h = 0; h < 2; ++h) {
      f16x8 af[4], bf[4];
#pragma unroll
      for (int mi = 0; mi < 4; ++mi)
        af[mi] = *(const f16x8*)&As[h][(wm + mi * 16 + ln) * 32 + quad * 8];
#pragma unroll
      for (int ni = 0; ni < 4; ++ni)
        bf[ni] = *(const f16x8*)&Ws[h][(wn + ni * 16 + ln) * 32 + quad * 8];
#pragma unroll
      for (int mi = 0; mi < 4; ++mi)
#pragma unroll
        for (int ni = 0; ni < 4; ++ni)
          acc[mi][ni] = __builtin_amdgcn_mfma_f32_16x16x32_f16(
              af[mi], bf[ni], acc[mi][ni], 0, 0, 0);
    }
    __syncthreads();
  }

  // fold 1/sqrt(Dh) * log2(e) into Q so attention uses exp2
  const float scale = (z == 0) ? 0.18033688f : 1.0f;

#pragma unroll
  for (int ni = 0; ni < 4; ++ni) {
    const int c = n0 + wn + ni * 16 + ln;
    const float bias_c = bias[c];
    const int h = c >> 6, d = c & 63;
#pragma unroll
    for (int mi = 0; mi < 4; ++mi) {
      const int mb = m0 + wm + mi * 16 + quad * 4;
#pragma unroll
      for (int r = 0; r < 4; ++r) {
        const int mg = mb + r;
        const int b = mg >> 11, s = mg & 2047;
        const int bh = b * NH + h;
        const float v = (acc[mi][ni][r] + bias_c) * scale;
        size_t idx;
        if (z == 2)
          idx = (size_t)bh * 131072 + (s >> 5) * 2048 + (d >> 4) * 512 +
                ((s >> 3) & 3) * 128 + (d & 15) * 8 + (s & 7);
        else
          idx = (size_t)bh * 131072 + (s >> 4) * 1024 + (d >> 5) * 512 +
                ((d >> 3) & 3) * 128 + (s & 15) * 8 + (d & 7);
        out[idx] = (_Float16)v;
      }
    }
  }
}

// ------------- output GEMM (BK=64 two-slab, 128x64 tile, direct) ------------

__global__ __launch_bounds__(256, 2) void gemm_out_kernel(
    const _Float16* __restrict__ ob, const _Float16* __restrict__ wo,
    const float* __restrict__ bo, float* __restrict__ out)
{
  __shared__ _Float16 As[2][128 * 32];
  __shared__ _Float16 Ws[2][64 * 32];
  const f32x4 z4 = {0.f, 0.f, 0.f, 0.f};
  f32x4 acc[2][4];
#pragma unroll
  for (int mi = 0; mi < 2; ++mi)
#pragma unroll
    for (int ni = 0; ni < 4; ++ni) acc[mi][ni] = z4;

  const int m0 = blockIdx.y * 128, n0 = blockIdx.x * 64;
  const int t = threadIdx.x;
  const int w = t >> 6, l = t & 63;
  const int quad = l >> 4, ln = l & 15;
  const int srow = l >> 2, scol = (l & 3) << 3;

  for (int k0 = 0; k0 < DM; k0 += 64) {
#pragma unroll
    for (int h = 0; h < 2; ++h) {
#pragma unroll
      for (int i = 0; i < 2; ++i) {
        const int ra = w * 32 + i * 16;
        gload_lds16(&ob[(size_t)(m0 + ra + srow) * DM + k0 + h * 32 + scol],
                    &As[h][ra * 32]);
      }
      gload_lds16(&wo[(size_t)(n0 + w * 16 + srow) * DM + k0 + h * 32 + scol],
                  &Ws[h][w * 16 * 32]);
    }
    __syncthreads();

#pragma unroll
    for (int h = 0; h < 2; ++h) {
      f16x8 af[2], bf[4];
#pragma unroll
      for (int mi = 0; mi < 2; ++mi)
        af[mi] = *(const f16x8*)&As[h][(w * 32 + mi * 16 + ln) * 32 + quad * 8];
#pragma unroll
      for (int ni = 0; ni < 4; ++ni)
        bf[ni] = *(const f16x8*)&Ws[h][(ni * 16 + ln) * 32 + quad * 8];
#pragma unroll
      for (int mi = 0; mi < 2; ++mi)
#pragma unroll
        for (int ni = 0; ni < 4; ++ni)
          acc[mi][ni] = __builtin_amdgcn_mfma_f32_16x16x32_f16(
              af[mi], bf[ni], acc[mi][ni], 0, 0, 0);
    }
    __syncthreads();
  }

#pragma unroll
  for (int ni = 0; ni < 4; ++ni) {
    const int c = n0 + ni * 16 + ln;
    const float bias_c = bo[c];
#pragma unroll
    for (int mi = 0; mi < 2; ++mi) {
      const int mb = m0 + w * 32 + mi * 16 + quad * 4;
#pragma unroll
      for (int r = 0; r < 4; ++r)
        out[(size_t)(mb + r) * DM + c] = acc[mi][ni][r] + bias_c;
    }
  }
}

// ---------------------------- flash attention ------------------------------
// 1024 blocks x 4 waves. Block = (head bh, pair p): wave w takes kv tiles
// t == w (mod 4) for q-tiles {63-p, p}. K fragments PREFETCHED one tile
// ahead (S-MFMA never waits on a just-issued load); V loaded in-tile
// (latency hidden behind softmax). Partial (O,l) merged via LDS.

template <bool DIAG>
__device__ __forceinline__ void compute_tile(
    const f16x8 (&kf)[4], const _Float16* __restrict__ vb_,
    int t, const f16x8 (&qf)[2][2], f32x4 (&oacc)[4][2],
    float (&l_i)[2], _Float16* Ps, int quad, int ln, int l)
{
  f16x8 vf[4];
#pragma unroll
  for (int i = 0; i < 4; ++i)
    vf[i] = *(const f16x8*)(vb_ + (size_t)(t * 4 + i) * 512 + l * 8);

  const f32x4 z4 = {0.f, 0.f, 0.f, 0.f};
  f32x4 sacc[2][2];
#pragma unroll
  for (int mi = 0; mi < 2; ++mi)
#pragma unroll
    for (int qc = 0; qc < 2; ++qc) sacc[mi][qc] = z4;

#pragma unroll
  for (int ks = 0; ks < 2; ++ks)
#pragma unroll
    for (int mi = 0; mi < 2; ++mi)
#pragma unroll
      for (int qc = 0; qc < 2; ++qc)
        sacc[mi][qc] = __builtin_amdgcn_mfma_f32_16x16x32_f16(
            kf[mi * 2 + ks], qf[qc][ks], sacc[mi][qc], 0, 0, 0);

  const int sw = (ln & 3) << 1;
#pragma unroll
  for (int qc = 0; qc < 2; ++qc) {
    float rs = 0.f;
#pragma unroll
    for (int mi = 0; mi < 2; ++mi) {
      float p[4];
#pragma unroll
      for (int r = 0; r < 4; ++r) {
        p[r] = __builtin_amdgcn_exp2f(sacc[mi][qc][r]);
        if (DIAG && (mi * 16 + quad * 4 + r > qc * 16 + ln)) p[r] = 0.f;
        rs += p[r];
      }
      const f16x2 lo = pkrtz(p[0], p[1]);
      const f16x2 hi = pkrtz(p[2], p[3]);
      const f16x4 pk = __builtin_shufflevector(lo, hi, 0, 1, 2, 3);
      const int g = (mi * 4 + quad) ^ sw;
      *(f16x4*)&Ps[(qc * 16 + ln) * 40 + g * 4] = pk;
    }
    l_i[qc] += rs;
  }

  f16x8 pb[2];
#pragma unroll
  for (int qc = 0; qc < 2; ++qc) {
    const int g2 = (quad * 2) ^ sw;
    pb[qc] = *(const f16x8*)&Ps[(qc * 16 + ln) * 40 + g2 * 4];
  }

#pragma unroll
  for (int di = 0; di < 4; ++di)
#pragma unroll
    for (int qc = 0; qc < 2; ++qc)
      oacc[di][qc] = __builtin_amdgcn_mfma_f32_16x16x32_f16(
          vf[di], pb[qc], oacc[di][qc], 0, 0, 0);
}

__global__ __launch_bounds__(256, 3) void attn_kernel(
    const _Float16* __restrict__ QF, const _Float16* __restrict__ KF,
    const _Float16* __restrict__ VF, _Float16* __restrict__ Ob)
{
  __shared__ _Float16 Ps[4 * 32 * 40];
  __shared__ float mrg[3 * 64 * 34];

  const int i = blockIdx.x;
  const int bh = ((i & 7) << 2) | ((i >> 3) & 3);
  const int p = i >> 5;

  const int tid = threadIdx.x;
  const int w = tid >> 6, l = tid & 63;
  const int quad = l >> 4, ln = l & 15;

  const _Float16* qb_ = QF + (size_t)bh * 131072;
  const _Float16* kb_ = KF + (size_t)bh * 131072;
  const _Float16* vb_ = VF + (size_t)bh * 131072;
  _Float16* psw = Ps + w * (32 * 40);
  const int bidx = bh >> 4, h = bh & 15;

  const f32x4 z4 = {0.f, 0.f, 0.f, 0.f};

#pragma unroll
  for (int mem = 0; mem < 2; ++mem) {
    const int qw = (mem == 0) ? (63 - p) : p;
    const int q0 = qw << 5;

    f16x8 qf[2][2];
#pragma unroll
    for (int qc = 0; qc < 2; ++qc)
#pragma unroll
      for (int ks = 0; ks < 2; ++ks)
        qf[qc][ks] = *(const f16x8*)
            (qb_ + (size_t)((2 * qw + qc) * 2 + ks) * 512 + l * 8);

    f32x4 oacc[4][2];
#pragma unroll
    for (int di = 0; di < 4; ++di)
#pragma unroll
      for (int qc = 0; qc < 2; ++qc) oacc[di][qc] = z4;
    float l_i[2] = {0.f, 0.f};

    int t = w;
    if (t <= qw) {
      f16x8 kf[4];
#pragma unroll
      for (int i2 = 0; i2 < 4; ++i2)
        kf[i2] = *(const f16x8*)(kb_ + (size_t)(t * 4 + i2) * 512 + l * 8);
      while (t + 4 <= qw) {
        f16x8 kn[4];
#pragma unroll
        for (int i2 = 0; i2 < 4; ++i2)
          kn[i2] = *(const f16x8*)(kb_ + (size_t)((t + 4) * 4 + i2) * 512 + l * 8);
        compute_tile<false>(kf, vb_, t, qf, oacc, l_i, psw, quad, ln, l);
#pragma unroll
        for (int i2 = 0; i2 < 4; ++i2) kf[i2] = kn[i2];
        t += 4;
      }
      if (t == qw)
        compute_tile<true>(kf, vb_, t, qf, oacc, l_i, psw, quad, ln, l);
      else
        compute_tile<false>(kf, vb_, t, qf, oacc, l_i, psw, quad, ln, l);
    }

#pragma unroll
    for (int qc = 0; qc < 2; ++qc) {
      float s = l_i[qc];
      s += __shfl_xor(s, 16);
      s += __shfl_xor(s, 32);
      l_i[qc] = s;
    }

    if (w != 0) {
      float* m_ = &mrg[((w - 1) * 64 + l) * 34];
#pragma unroll
      for (int di = 0; di < 4; ++di)
#pragma unroll
        for (int qc = 0; qc < 2; ++qc)
          *(f32x4*)(m_ + di * 8 + qc * 4) = oacc[di][qc];
      m_[32] = l_i[0];
      m_[33] = l_i[1];
    }
    __syncthreads();
    if (w == 0) {
#pragma unroll
      for (int ww = 0; ww < 3; ++ww) {
        const float* m_ = &mrg[(ww * 64 + l) * 34];
#pragma unroll
        for (int di = 0; di < 4; ++di)
#pragma unroll
          for (int qc = 0; qc < 2; ++qc)
            oacc[di][qc] += *(const f32x4*)(m_ + di * 8 + qc * 4);
        l_i[0] += m_[32];
        l_i[1] += m_[33];
      }
#pragma unroll
      for (int qc = 0; qc < 2; ++qc) {
        const float inv = 1.0f / l_i[qc];
        const int q = q0 + qc * 16 + ln;
        _Float16* orow = Ob + (size_t)(bidx * S_ + q) * DM + h * DH + quad * 4;
#pragma unroll
        for (int di = 0; di < 4; ++di) {
          f16x4 o4;
#pragma unroll
          for (int r = 0; r < 4; ++r)
            o4[r] = (_Float16)(oacc[di][qc][r] * inv);
          *(f16x4*)(orow + di * 16) = o4;
        }
      }
    }
    __syncthreads();
  }
}

// ------------------------------- launcher ----------------------------------

extern "C" void kernel_launch(void* const* d_in, const int* in_sizes, int n_in,
                              void* d_out, int out_size, void* d_ws, size_t ws_size,
                              hipStream_t stream) {
  (void)in_sizes; (void)n_in; (void)out_size; (void)ws_size;
  const float* x  = (const float*)d_in[0];
  const float* Wq = (const float*)d_in[1];
  const float* bq = (const float*)d_in[2];
  const float* Wk = (const float*)d_in[3];
  const float* bk = (const float*)d_in[4];
  const float* Wv = (const float*)d_in[5];
  const float* bv = (const float*)d_in[6];
  const float* Wo = (const float*)d_in[7];
  const float* bo = (const float*)d_in[8];

  char* ws = (char*)d_ws;
  _Float16* xb  = (_Float16*)(ws);                      // 8 MB
  _Float16* wb  = (_Float16*)(ws + (8u << 20));         // 4 x 2 MB
  _Float16* qkv = (_Float16*)(ws + (16u << 20));        // QF,KF,VF 8 MB each
  _Float16* ob  = (_Float16*)(ws + (40u << 20));        // 8 MB

  cvt_all_kernel<<<dim3(8192), dim3(256), 0, stream>>>(x, Wq, Wk, Wv, Wo, xb, wb);
  gemm_qkv_kernel<<<dim3(8, 32, 3), dim3(256), 0, stream>>>(xb, wb, bq, bk, bv, qkv);
  attn_kernel<<<dim3(1024), dim3(256), 0, stream>>>(
      qkv, qkv + 4194304, qkv + 2 * 4194304, ob);
  gemm_out_kernel<<<dim3(16, 32), dim3(256), 0, stream>>>(
      ob, wb + (size_t)3 * DM * DM, bo, (float*)d_out);
}

// Round 12
// 176.479 us; speedup vs baseline: 2.5998x; 1.0238x over previous
//
#include <hip/hip_runtime.h>

// ---------------------------------------------------------------------------
// StandardMultiHeadAttention: B=2, S=2048, D=1024, H=16, Dh=64, causal.
// fp32->f16 convert (single kernel) -> QKV GEMM (BK=64, frag-major epilogue)
// -> flash attention (S^T tiles, static-base softmax) -> output GEMM (BK=64,
// 128x64 tiles, direct fp32 write + bias).
//
// Workspace (48 MB):
//   [0,8M)    xb : x f16 [4096,1024]
//   [8M,16M)  wb : Wq,Wk,Wv,Wo f16 (row=out, K-major)
//   [16M,24M) QF : Q frag-major (pre-scaled by 0.125*log2e)
//   [24M,32M) KF : K frag-major
//   [32M,40M) VF : V^T frag-major
//   [40M,48M) ob : attention output [B,S,1024] f16
//
// R11 post-mortem: attn latency-bound at 19.6% occupancy (3 blocks/CU, 1.33
// dispatch generations, ~1200 serial cyc/wave-tile vs ~300 issue); prefetch
// (ILP) couldn't help the serial exp->LDS->MFMA chain. R12: TLP instead —
// launch_bounds(256,4): 1024 blocks = 256 CU x 4 EXACTLY co-resident, 4
// waves/SIMD. Fits the 128-reg/wave cap only without prefetch (in-tile K+V
// loads, ~72 VGPR + 48 AGPR = 120 <= 128; R7's spill was the +32 dbuf).
// ---------------------------------------------------------------------------

typedef _Float16 f16x8 __attribute__((ext_vector_type(8)));
typedef _Float16 f16x4 __attribute__((ext_vector_type(4)));
typedef _Float16 f16x2 __attribute__((ext_vector_type(2)));
typedef float f32x4 __attribute__((ext_vector_type(4)));

#define S_  2048
#define DM  1024
#define NH  16
#define DH  64

__device__ __forceinline__ void gload_lds16(const void* g, void* s) {
  __builtin_amdgcn_global_load_lds(
      (const __attribute__((address_space(1))) void*)g,
      (__attribute__((address_space(3))) void*)s, 16, 0, 0);
}

__device__ __forceinline__ f16x2 pkrtz(float a, float b) {
  return __builtin_bit_cast(f16x2, __builtin_amdgcn_cvt_pkrtz(a, b));
}

// ----------------------------- convert kernel ------------------------------
// blocks [0,4096): x -> xb ; blocks [4096,8192): Wq..Wo -> wb

__global__ void cvt_all_kernel(const float* __restrict__ x,
                               const float* __restrict__ w0,
                               const float* __restrict__ w1,
                               const float* __restrict__ w2,
                               const float* __restrict__ w3,
                               _Float16* __restrict__ xb,
                               _Float16* __restrict__ wb) {
  const int bid = blockIdx.x;
  const float* src;
  _Float16* dst;
  int idx;
  if (bid < 4096) {
    src = x; dst = xb; idx = bid * 256 + threadIdx.x;
  } else {
    const int j = bid - 4096;
    const int y = j >> 10;
    src = (y == 0) ? w0 : (y == 1) ? w1 : (y == 2) ? w2 : w3;
    dst = wb + (size_t)y * (DM * DM);
    idx = (j & 1023) * 256 + threadIdx.x;
  }
  const float4 v = ((const float4*)src)[idx];
  f16x4 h;
  h[0] = (_Float16)v.x; h[1] = (_Float16)v.y;
  h[2] = (_Float16)v.z; h[3] = (_Float16)v.w;
  ((f16x4*)dst)[idx] = h;
}

// ------------------------- QKV GEMM (BK=64, 2 slabs) ------------------------
// z=0: Q (bias, *0.125*log2e, QF layout); z=1: K (KF); z=2: V (VF)

__global__ __launch_bounds__(256, 2) void gemm_qkv_kernel(
    const _Float16* __restrict__ xb, const _Float16* __restrict__ wb,
    const float* __restrict__ bq, const float* __restrict__ bk,
    const float* __restrict__ bv, _Float16* __restrict__ qkv)
{
  __shared__ _Float16 As[2][128 * 32];   // slab h: k in [k0+32h, k0+32h+32)
  __shared__ _Float16 Ws[2][128 * 32];
  const int z = blockIdx.z;
  const _Float16* W = wb + (size_t)z * (DM * DM);
  const float* bias = (z == 0) ? bq : ((z == 1) ? bk : bv);
  _Float16* out = qkv + (size_t)z * 4194304;

  const f32x4 z4 = {0.f, 0.f, 0.f, 0.f};
  f32x4 acc[4][4];
#pragma unroll
  for (int mi = 0; mi < 4; ++mi)
#pragma unroll
    for (int ni = 0; ni < 4; ++ni) acc[mi][ni] = z4;

  const int m0 = blockIdx.y * 128, n0 = blockIdx.x * 128;
  const int t = threadIdx.x;
  const int w = t >> 6, l = t & 63;
  const int quad = l >> 4, ln = l & 15;
  const int wm = (w >> 1) << 6, wn = (w & 1) << 6;
  const int srow = l >> 2, scol = (l & 3) << 3;

  for (int k0 = 0; k0 < DM; k0 += 64) {
#pragma unroll
    for (int h = 0; h < 2; ++h)
#pragma unroll
      for (int i = 0; i < 2; ++i) {
        const int ra = w * 32 + i * 16;
        gload_lds16(&xb[(size_t)(m0 + ra + srow) * DM + k0 + h * 32 + scol],
                    &As[h][ra * 32]);
        gload_lds16(&W[(size_t)(n0 + ra + srow) * DM + k0 + h * 32 + scol],
                    &Ws[h][ra * 32]);
      }
    __syncthreads();

#pragma unroll
    for (int h = 0; h < 2; ++h) {
      f16x8 af[4], bf[4];
#pragma unroll
      for (int mi = 0; mi < 4; ++mi)
        af[mi] = *(const f16x8*)&As[h][(wm + mi * 16 + ln) * 32 + quad * 8];
#pragma unroll
      for (int ni = 0; ni < 4; ++ni)
        bf[ni] = *(const f16x8*)&Ws[h][(wn + ni * 16 + ln) * 32 + quad * 8];
#pragma unroll
      for (int mi = 0; mi < 4; ++mi)
#pragma unroll
        for (int ni = 0; ni < 4; ++ni)
          acc[mi][ni] = __builtin_amdgcn_mfma_f32_16x16x32_f16(
              af[mi], bf[ni], acc[mi][ni], 0, 0, 0);
    }
    __syncthreads();
  }

  // fold 1/sqrt(Dh) * log2(e) into Q so attention uses exp2
  const float scale = (z == 0) ? 0.18033688f : 1.0f;

#pragma unroll
  for (int ni = 0; ni < 4; ++ni) {
    const int c = n0 + wn + ni * 16 + ln;
    const float bias_c = bias[c];
    const int h = c >> 6, d = c & 63;
#pragma unroll
    for (int mi = 0; mi < 4; ++mi) {
      const int mb = m0 + wm + mi * 16 + quad * 4;
#pragma unroll
      for (int r = 0; r < 4; ++r) {
        const int mg = mb + r;
        const int b = mg >> 11, s = mg & 2047;
        const int bh = b * NH + h;
        const float v = (acc[mi][ni][r] + bias_c) * scale;
        size_t idx;
        if (z == 2)
          idx = (size_t)bh * 131072 + (s >> 5) * 2048 + (d >> 4) * 512 +
                ((s >> 3) & 3) * 128 + (d & 15) * 8 + (s & 7);
        else
          idx = (size_t)bh * 131072 + (s >> 4) * 1024 + (d >> 5) * 512 +
                ((d >> 3) & 3) * 128 + (s & 15) * 8 + (d & 7);
        out[idx] = (_Float16)v;
      }
    }
  }
}

// ------------- output GEMM (BK=64 two-slab, 128x64 tile, direct) ------------

__global__ __launch_bounds__(256, 2) void gemm_out_kernel(
    const _Float16* __restrict__ ob, const _Float16* __restrict__ wo,
    const float* __restrict__ bo, float* __restrict__ out)
{
  __shared__ _Float16 As[2][128 * 32];
  __shared__ _Float16 Ws[2][64 * 32];
  const f32x4 z4 = {0.f, 0.f, 0.f, 0.f};
  f32x4 acc[2][4];
#pragma unroll
  for (int mi = 0; mi < 2; ++mi)
#pragma unroll
    for (int ni = 0; ni < 4; ++ni) acc[mi][ni] = z4;

  const int m0 = blockIdx.y * 128, n0 = blockIdx.x * 64;
  const int t = threadIdx.x;
  const int w = t >> 6, l = t & 63;
  const int quad = l >> 4, ln = l & 15;
  const int srow = l >> 2, scol = (l & 3) << 3;

  for (int k0 = 0; k0 < DM; k0 += 64) {
#pragma unroll
    for (int h = 0; h < 2; ++h) {
#pragma unroll
      for (int i = 0; i < 2; ++i) {
        const int ra = w * 32 + i * 16;
        gload_lds16(&ob[(size_t)(m0 + ra + srow) * DM + k0 + h * 32 + scol],
                    &As[h][ra * 32]);
      }
      gload_lds16(&wo[(size_t)(n0 + w * 16 + srow) * DM + k0 + h * 32 + scol],
                  &Ws[h][w * 16 * 32]);
    }
    __syncthreads();

#pragma unroll
    for (int h = 0; h < 2; ++h) {
      f16x8 af[2], bf[4];
#pragma unroll
      for (int mi = 0; mi < 2; ++mi)
        af[mi] = *(const f16x8*)&As[h][(w * 32 + mi * 16 + ln) * 32 + quad * 8];
#pragma unroll
      for (int ni = 0; ni < 4; ++ni)
        bf[ni] = *(const f16x8*)&Ws[h][(ni * 16 + ln) * 32 + quad * 8];
#pragma unroll
      for (int mi = 0; mi < 2; ++mi)
#pragma unroll
        for (int ni = 0; ni < 4; ++ni)
          acc[mi][ni] = __builtin_amdgcn_mfma_f32_16x16x32_f16(
              af[mi], bf[ni], acc[mi][ni], 0, 0, 0);
    }
    __syncthreads();
  }

#pragma unroll
  for (int ni = 0; ni < 4; ++ni) {
    const int c = n0 + ni * 16 + ln;
    const float bias_c = bo[c];
#pragma unroll
    for (int mi = 0; mi < 2; ++mi) {
      const int mb = m0 + w * 32 + mi * 16 + quad * 4;
#pragma unroll
      for (int r = 0; r < 4; ++r)
        out[(size_t)(mb + r) * DM + c] = acc[mi][ni][r] + bias_c;
    }
  }
}

// ---------------------------- flash attention ------------------------------
// 1024 blocks x 4 waves = 256 CU x 4 blocks EXACTLY co-resident at
// launch_bounds(256,4) (4 waves/SIMD TLP; no dispatch tail). Block = (head
// bh, pair p): wave w takes kv tiles t == w (mod 4) for q-tiles {63-p, p}.
// In-tile K+V loads (no prefetch: keeps unified regs ~120 <= 128 cap).
// Partial (O,l) merged via LDS; l quad-reduction deferred.

template <bool DIAG>
__device__ __forceinline__ void compute_tile(
    const _Float16* __restrict__ kb_, const _Float16* __restrict__ vb_,
    int t, const f16x8 (&qf)[2][2], f32x4 (&oacc)[4][2],
    float (&l_i)[2], _Float16* Ps, int quad, int ln, int l)
{
  f16x8 kf[4], vf[4];
#pragma unroll
  for (int i = 0; i < 4; ++i)
    kf[i] = *(const f16x8*)(kb_ + (size_t)(t * 4 + i) * 512 + l * 8);
#pragma unroll
  for (int i = 0; i < 4; ++i)
    vf[i] = *(const f16x8*)(vb_ + (size_t)(t * 4 + i) * 512 + l * 8);

  const f32x4 z4 = {0.f, 0.f, 0.f, 0.f};
  f32x4 sacc[2][2];
#pragma unroll
  for (int mi = 0; mi < 2; ++mi)
#pragma unroll
    for (int qc = 0; qc < 2; ++qc) sacc[mi][qc] = z4;

#pragma unroll
  for (int ks = 0; ks < 2; ++ks)
#pragma unroll
    for (int mi = 0; mi < 2; ++mi)
#pragma unroll
      for (int qc = 0; qc < 2; ++qc)
        sacc[mi][qc] = __builtin_amdgcn_mfma_f32_16x16x32_f16(
            kf[mi * 2 + ks], qf[qc][ks], sacc[mi][qc], 0, 0, 0);

  const int sw = (ln & 3) << 1;
#pragma unroll
  for (int qc = 0; qc < 2; ++qc) {
    float rs = 0.f;
#pragma unroll
    for (int mi = 0; mi < 2; ++mi) {
      float p[4];
#pragma unroll
      for (int r = 0; r < 4; ++r) {
        p[r] = __builtin_amdgcn_exp2f(sacc[mi][qc][r]);
        if (DIAG && (mi * 16 + quad * 4 + r > qc * 16 + ln)) p[r] = 0.f;
        rs += p[r];
      }
      const f16x2 lo = pkrtz(p[0], p[1]);
      const f16x2 hi = pkrtz(p[2], p[3]);
      const f16x4 pk = __builtin_shufflevector(lo, hi, 0, 1, 2, 3);
      const int g = (mi * 4 + quad) ^ sw;
      *(f16x4*)&Ps[(qc * 16 + ln) * 40 + g * 4] = pk;
    }
    l_i[qc] += rs;
  }

  f16x8 pb[2];
#pragma unroll
  for (int qc = 0; qc < 2; ++qc) {
    const int g2 = (quad * 2) ^ sw;
    pb[qc] = *(const f16x8*)&Ps[(qc * 16 + ln) * 40 + g2 * 4];
  }

#pragma unroll
  for (int di = 0; di < 4; ++di)
#pragma unroll
    for (int qc = 0; qc < 2; ++qc)
      oacc[di][qc] = __builtin_amdgcn_mfma_f32_16x16x32_f16(
          vf[di], pb[qc], oacc[di][qc], 0, 0, 0);
}

__global__ __launch_bounds__(256, 4) void attn_kernel(
    const _Float16* __restrict__ QF, const _Float16* __restrict__ KF,
    const _Float16* __restrict__ VF, _Float16* __restrict__ Ob)
{
  __shared__ _Float16 Ps[4 * 32 * 40];
  __shared__ float mrg[3 * 64 * 34];

  const int i = blockIdx.x;
  const int bh = ((i & 7) << 2) | ((i >> 3) & 3);
  const int p = i >> 5;

  const int tid = threadIdx.x;
  const int w = tid >> 6, l = tid & 63;
  const int quad = l >> 4, ln = l & 15;

  const _Float16* qb_ = QF + (size_t)bh * 131072;
  const _Float16* kb_ = KF + (size_t)bh * 131072;
  const _Float16* vb_ = VF + (size_t)bh * 131072;
  _Float16* psw = Ps + w * (32 * 40);
  const int bidx = bh >> 4, h = bh & 15;

  const f32x4 z4 = {0.f, 0.f, 0.f, 0.f};

#pragma unroll
  for (int mem = 0; mem < 2; ++mem) {
    const int qw = (mem == 0) ? (63 - p) : p;
    const int q0 = qw << 5;

    f16x8 qf[2][2];
#pragma unroll
    for (int qc = 0; qc < 2; ++qc)
#pragma unroll
      for (int ks = 0; ks < 2; ++ks)
        qf[qc][ks] = *(const f16x8*)
            (qb_ + (size_t)((2 * qw + qc) * 2 + ks) * 512 + l * 8);

    f32x4 oacc[4][2];
#pragma unroll
    for (int di = 0; di < 4; ++di)
#pragma unroll
      for (int qc = 0; qc < 2; ++qc) oacc[di][qc] = z4;
    float l_i[2] = {0.f, 0.f};

    int t = w;
    for (; t < qw; t += 4)
      compute_tile<false>(kb_, vb_, t, qf, oacc, l_i, psw, quad, ln, l);
    if (t == qw)
      compute_tile<true>(kb_, vb_, t, qf, oacc, l_i, psw, quad, ln, l);

#pragma unroll
    for (int qc = 0; qc < 2; ++qc) {
      float s = l_i[qc];
      s += __shfl_xor(s, 16);
      s += __shfl_xor(s, 32);
      l_i[qc] = s;
    }

    if (w != 0) {
      float* m_ = &mrg[((w - 1) * 64 + l) * 34];
#pragma unroll
      for (int di = 0; di < 4; ++di)
#pragma unroll
        for (int qc = 0; qc < 2; ++qc)
          *(f32x4*)(m_ + di * 8 + qc * 4) = oacc[di][qc];
      m_[32] = l_i[0];
      m_[33] = l_i[1];
    }
    __syncthreads();
    if (w == 0) {
#pragma unroll
      for (int ww = 0; ww < 3; ++ww) {
        const float* m_ = &mrg[(ww * 64 + l) * 34];
#pragma unroll
        for (int di = 0; di < 4; ++di)
#pragma unroll
          for (int qc = 0; qc < 2; ++qc)
            oacc[di][qc] += *(const f32x4*)(m_ + di * 8 + qc * 4);
        l_i[0] += m_[32];
        l_i[1] += m_[33];
      }
#pragma unroll
      for (int qc = 0; qc < 2; ++qc) {
        const float inv = 1.0f / l_i[qc];
        const int q = q0 + qc * 16 + ln;
        _Float16* orow = Ob + (size_t)(bidx * S_ + q) * DM + h * DH + quad * 4;
#pragma unroll
        for (int di = 0; di < 4; ++di) {
          f16x4 o4;
#pragma unroll
          for (int r = 0; r < 4; ++r)
            o4[r] = (_Float16)(oacc[di][qc][r] * inv);
          *(f16x4*)(orow + di * 16) = o4;
        }
      }
    }
    __syncthreads();
  }
}

// ------------------------------- launcher ----------------------------------

extern "C" void kernel_launch(void* const* d_in, const int* in_sizes, int n_in,
                              void* d_out, int out_size, void* d_ws, size_t ws_size,
                              hipStream_t stream) {
  (void)in_sizes; (void)n_in; (void)out_size; (void)ws_size;
  const float* x  = (const float*)d_in[0];
  const float* Wq = (const float*)d_in[1];
  const float* bq = (const float*)d_in[2];
  const float* Wk = (const float*)d_in[3];
  const float* bk = (const float*)d_in[4];
  const float* Wv = (const float*)d_in[5];
  const float* bv = (const float*)d_in[6];
  const float* Wo = (const float*)d_in[7];
  const float* bo = (const float*)d_in[8];

  char* ws = (char*)d_ws;
  _Float16* xb  = (_Float16*)(ws);                      // 8 MB
  _Float16* wb  = (_Float16*)(ws + (8u << 20));         // 4 x 2 MB
  _Float16* qkv = (_Float16*)(ws + (16u << 20));        // QF,KF,VF 8 MB each
  _Float16* ob  = (_Float16*)(ws + (40u << 20));        // 8 MB

  cvt_all_kernel<<<dim3(8192), dim3(256), 0, stream>>>(x, Wq, Wk, Wv, Wo, xb, wb);
  gemm_qkv_kernel<<<dim3(8, 32, 3), dim3(256), 0, stream>>>(xb, wb, bq, bk, bv, qkv);
  attn_kernel<<<dim3(1024), dim3(256), 0, stream>>>(
      qkv, qkv + 4194304, qkv + 2 * 4194304, ob);
  gemm_out_kernel<<<dim3(16, 32), dim3(256), 0, stream>>>(
      ob, wb + (size_t)3 * DM * DM, bo, (float*)d_out);
}